// Round 1
// baseline (1244.791 us; speedup 1.0000x reference)
//
#include <hip/hip_runtime.h>
#include <hip/hip_bf16.h>

// Problem dims (fixed by setup_inputs): B=64, N=16384, D=1024, A=2048, H=8
#define NB 64
#define NN 16384
#define ND 1024
#define NA 2048
#define NH 8

// ---------------------------------------------------------------- seg offsets
__global__ void k_segoff(const int* __restrict__ segnum, int* __restrict__ segoff) {
    if (threadIdx.x == 0) {
        int a = 0;
        segoff[0] = 0;
        for (int b = 0; b < NB; b++) { a += segnum[b]; segoff[b + 1] = a; }
    }
}

// ------------------------------------------------- h = relu(x@w1)@w2  (split-A)
// grid (N/64, A/128), block 256. Each block: 64x128 tile of c1=relu(x@w1),
// then * w2[chunk,8] -> atomicAdd into h[N,8].
__global__ __launch_bounds__(256) void k_h_gemm(const float* __restrict__ x,
                                                const float* __restrict__ w1,
                                                const float* __restrict__ w2,
                                                float* __restrict__ h) {
    __shared__ float xs[32][68];    // transposed x tile: xs[k][m], pad row to 68
    __shared__ float w1s[32][128];  // w1 tile [k][n]
    __shared__ float w2s[128][NH];

    const int tid = threadIdx.x;
    const int m0 = blockIdx.x * 64;
    const int n0 = blockIdx.y * 128;

    // stage w2 chunk (coalesced: flat copy)
    for (int i = tid; i < 128 * NH; i += 256)
        ((float*)w2s)[i] = w2[(size_t)n0 * NH + i];

    const int tr = tid >> 4;   // 0..15 -> rows tr*4..tr*4+3
    const int tc = tid & 15;   // 0..15 -> cols tc*8..tc*8+7

    float acc[4][8];
#pragma unroll
    for (int i = 0; i < 4; i++)
#pragma unroll
        for (int j = 0; j < 8; j++) acc[i][j] = 0.f;

    for (int k0 = 0; k0 < ND; k0 += 32) {
        __syncthreads();
        {   // load x tile 64x32, store transposed
            int r = tid >> 2;
            int c = (tid & 3) * 8;
            const float4* gp = (const float4*)(x + (size_t)(m0 + r) * ND + k0 + c);
            float4 v0 = gp[0], v1 = gp[1];
            xs[c + 0][r] = v0.x; xs[c + 1][r] = v0.y; xs[c + 2][r] = v0.z; xs[c + 3][r] = v0.w;
            xs[c + 4][r] = v1.x; xs[c + 5][r] = v1.y; xs[c + 6][r] = v1.z; xs[c + 7][r] = v1.w;
        }
        {   // load w1 tile 32x128
            int r = tid >> 3;
            int c = (tid & 7) * 16;
            const float4* gp = (const float4*)(w1 + (size_t)(k0 + r) * NA + n0 + c);
            float4* sp = (float4*)&w1s[r][c];
            sp[0] = gp[0]; sp[1] = gp[1]; sp[2] = gp[2]; sp[3] = gp[3];
        }
        __syncthreads();
#pragma unroll
        for (int k = 0; k < 32; k++) {
            float4 a  = *(const float4*)&xs[k][tr * 4];
            float4 b0 = *(const float4*)&w1s[k][tc * 8];
            float4 b1 = *(const float4*)&w1s[k][tc * 8 + 4];
            float av[4] = {a.x, a.y, a.z, a.w};
            float bv[8] = {b0.x, b0.y, b0.z, b0.w, b1.x, b1.y, b1.z, b1.w};
#pragma unroll
            for (int i = 0; i < 4; i++)
#pragma unroll
                for (int j = 0; j < 8; j++) acc[i][j] += av[i] * bv[j];
        }
    }

    // epilogue: relu, * w2 chunk, reduce over tc groups, atomicAdd into h
    float ph[4][NH];
#pragma unroll
    for (int i = 0; i < 4; i++)
#pragma unroll
        for (int q = 0; q < NH; q++) ph[i][q] = 0.f;

#pragma unroll
    for (int j = 0; j < 8; j++) {
        int n = tc * 8 + j;
#pragma unroll
        for (int i = 0; i < 4; i++) {
            float v = fmaxf(acc[i][j], 0.f);
#pragma unroll
            for (int q = 0; q < NH; q++) ph[i][q] += v * w2s[n][q];
        }
    }

#pragma unroll
    for (int i = 0; i < 4; i++)
#pragma unroll
        for (int q = 0; q < NH; q++) {
            float v = ph[i][q];
            v += __shfl_xor(v, 1);
            v += __shfl_xor(v, 2);
            v += __shfl_xor(v, 4);
            v += __shfl_xor(v, 8);
            if (tc == 0) atomicAdd(&h[(size_t)(m0 + tr * 4 + i) * NH + q], v);
        }
}

// ------------------------------------------------ per-segment softmax -> attn
__global__ __launch_bounds__(256) void k_softmax(const float* __restrict__ h,
                                                 float* __restrict__ attn,
                                                 const int* __restrict__ segoff) {
    const int b = blockIdx.x;
    const int s0 = segoff[b], s1 = segoff[b + 1];
    const int tid = threadIdx.x;
    __shared__ float red[4][NH];
    __shared__ float mb[NH];
    __shared__ float sinv[NH];

    float mx[NH];
#pragma unroll
    for (int q = 0; q < NH; q++) mx[q] = -1e30f;
    for (int n = s0 + tid; n < s1; n += 256) {
        const float* hr = &h[(size_t)n * NH];
#pragma unroll
        for (int q = 0; q < NH; q++) mx[q] = fmaxf(mx[q], hr[q]);
    }
#pragma unroll
    for (int q = 0; q < NH; q++)
        for (int o = 1; o < 64; o <<= 1) mx[q] = fmaxf(mx[q], __shfl_xor(mx[q], o));
    const int wv = tid >> 6;
    if ((tid & 63) == 0)
        for (int q = 0; q < NH; q++) red[wv][q] = mx[q];
    __syncthreads();
    if (tid < NH)
        mb[tid] = fmaxf(fmaxf(red[0][tid], red[1][tid]), fmaxf(red[2][tid], red[3][tid]));
    __syncthreads();

    float sm[NH];
#pragma unroll
    for (int q = 0; q < NH; q++) sm[q] = 0.f;
    for (int n = s0 + tid; n < s1; n += 256) {
        const float* hr = &h[(size_t)n * NH];
#pragma unroll
        for (int q = 0; q < NH; q++) sm[q] += expf(hr[q] - mb[q]);
    }
#pragma unroll
    for (int q = 0; q < NH; q++)
        for (int o = 1; o < 64; o <<= 1) sm[q] += __shfl_xor(sm[q], o);
    if ((tid & 63) == 0)
        for (int q = 0; q < NH; q++) red[wv][q] = sm[q];
    __syncthreads();
    if (tid < NH)
        sinv[tid] = 1.0f / (red[0][tid] + red[1][tid] + red[2][tid] + red[3][tid]);
    __syncthreads();

    for (int n = s0 + tid; n < s1; n += 256) {
        const float* hr = &h[(size_t)n * NH];
        float* ar = &attn[(size_t)n * NH];
#pragma unroll
        for (int q = 0; q < NH; q++) ar[q] = expf(hr[q] - mb[q]) * sinv[q];
    }
}

// --------------------- out_bdh[b,d,h] = sum_n x[n,d]*attn[n,h]; + out_segment
// grid (D/128, B), block 256 (128 d-lanes x 2 frame-offsets)
__global__ __launch_bounds__(256) void k_bdh(const float* __restrict__ x,
                                             const float* __restrict__ attn,
                                             const int* __restrict__ segoff,
                                             float* __restrict__ bdh,
                                             float* __restrict__ out_segment) {
    const int b = blockIdx.y;
    const int d0 = blockIdx.x * 128;
    const int s0 = segoff[b], s1 = segoff[b + 1];
    const int dl = threadIdx.x & 127;
    const int d = d0 + dl;
    const int fo = threadIdx.x >> 7;

    float acc[NH];
#pragma unroll
    for (int q = 0; q < NH; q++) acc[q] = 0.f;
    float asum = 0.f;

    for (int n = s0 + fo; n < s1; n += 2) {
        float xv = x[(size_t)n * ND + d];
        const float4* ap = (const float4*)&attn[(size_t)n * NH];
        float4 a0 = ap[0], a1 = ap[1];
        acc[0] += xv * a0.x; acc[1] += xv * a0.y; acc[2] += xv * a0.z; acc[3] += xv * a0.w;
        acc[4] += xv * a1.x; acc[5] += xv * a1.y; acc[6] += xv * a1.z; acc[7] += xv * a1.w;
        asum += xv;
    }

    __shared__ float red[128][NH + 1];
    if (fo == 1) {
#pragma unroll
        for (int q = 0; q < NH; q++) red[dl][q] = acc[q];
        red[dl][NH] = asum;
    }
    __syncthreads();
    if (fo == 0) {
#pragma unroll
        for (int q = 0; q < NH; q++) acc[q] += red[dl][q];
        asum += red[dl][NH];
        float* bp = &bdh[(size_t)b * (ND * NH) + (size_t)d * NH];
#pragma unroll
        for (int q = 0; q < NH; q++) bp[q] = acc[q];
        out_segment[(size_t)b * ND + d] = asum / (float)(s1 - s0);
    }
}

// ------------------------------------------------- attn_gram[b] = attn^T@attn
__global__ __launch_bounds__(256) void k_gram(const float* __restrict__ attn,
                                              const int* __restrict__ segoff,
                                              float* __restrict__ gram) {
    const int b = blockIdx.x;
    const int s0 = segoff[b], s1 = segoff[b + 1];
    const int p = threadIdx.x & 63;
    const int g = threadIdx.x >> 6;
    const int i = p >> 3, j = p & 7;
    float acc = 0.f;
    for (int n = s0 + g; n < s1; n += 4)
        acc += attn[(size_t)n * NH + i] * attn[(size_t)n * NH + j];
    __shared__ float red[4][64];
    red[g][p] = acc;
    __syncthreads();
    if (g == 0)
        gram[(size_t)b * 64 + p] = red[0][p] + red[1][p] + red[2][p] + red[3][p];
}

// ------------------------------------- out = bdh[64,8192] @ w_post[8192,1024]
// grid (1024/128, 8192/512) split-K, block 256, atomicAdd epilogue
__global__ __launch_bounds__(256) void k_post(const float* __restrict__ bdh,
                                              const float* __restrict__ wp,
                                              float* __restrict__ out) {
    __shared__ float as[32][68];   // transposed bdh chunk: as[k][m]
    __shared__ float bs[32][128];
    const int tid = threadIdx.x;
    const int n0 = blockIdx.x * 128;
    const int k0 = blockIdx.y * 512;
    const int tr = tid >> 4, tc = tid & 15;

    float acc[4][8];
#pragma unroll
    for (int i = 0; i < 4; i++)
#pragma unroll
        for (int j = 0; j < 8; j++) acc[i][j] = 0.f;

    for (int kc = 0; kc < 512; kc += 32) {
        __syncthreads();
        {
            int r = tid >> 2;
            int c = (tid & 3) * 8;
            const float4* gp = (const float4*)(bdh + (size_t)r * (ND * NH) + k0 + kc + c);
            float4 v0 = gp[0], v1 = gp[1];
            as[c + 0][r] = v0.x; as[c + 1][r] = v0.y; as[c + 2][r] = v0.z; as[c + 3][r] = v0.w;
            as[c + 4][r] = v1.x; as[c + 5][r] = v1.y; as[c + 6][r] = v1.z; as[c + 7][r] = v1.w;
        }
        {
            int r = tid >> 3;
            int c = (tid & 7) * 16;
            const float4* gp = (const float4*)(wp + (size_t)(k0 + kc + r) * ND + n0 + c);
            float4* sp = (float4*)&bs[r][c];
            sp[0] = gp[0]; sp[1] = gp[1]; sp[2] = gp[2]; sp[3] = gp[3];
        }
        __syncthreads();
#pragma unroll
        for (int k = 0; k < 32; k++) {
            float4 a  = *(const float4*)&as[k][tr * 4];
            float4 b0 = *(const float4*)&bs[k][tc * 8];
            float4 b1 = *(const float4*)&bs[k][tc * 8 + 4];
            float av[4] = {a.x, a.y, a.z, a.w};
            float bv[8] = {b0.x, b0.y, b0.z, b0.w, b1.x, b1.y, b1.z, b1.w};
#pragma unroll
            for (int i = 0; i < 4; i++)
#pragma unroll
                for (int j = 0; j < 8; j++) acc[i][j] += av[i] * bv[j];
        }
    }

#pragma unroll
    for (int i = 0; i < 4; i++)
#pragma unroll
        for (int j = 0; j < 8; j++)
            atomicAdd(&out[(size_t)(tr * 4 + i) * ND + n0 + tc * 8 + j], acc[i][j]);
}

extern "C" void kernel_launch(void* const* d_in, const int* in_sizes, int n_in,
                              void* d_out, int out_size, void* d_ws, size_t ws_size,
                              hipStream_t stream) {
    (void)in_sizes; (void)n_in; (void)out_size; (void)ws_size;
    const float* x      = (const float*)d_in[0];
    const int*   segnum = (const int*)d_in[1];
    const float* w1     = (const float*)d_in[2];
    const float* w2     = (const float*)d_in[3];
    const float* wpost  = (const float*)d_in[4];

    float* out         = (float*)d_out;            // [64*1024]
    float* out_segment = out + NB * ND;            // [64*1024]
    float* gram        = out + 2 * NB * ND;        // [64*64]

    char* ws = (char*)d_ws;
    int*   segoff = (int*)ws;                                  // 65 ints
    float* h      = (float*)(ws + 1024);                       // N*8
    float* attn   = (float*)(ws + 1024 + (size_t)NN * NH * 4); // N*8
    float* bdh    = (float*)(ws + 1024 + 2 * (size_t)NN * NH * 4); // 64*8192

    hipMemsetAsync(h, 0, (size_t)NN * NH * 4, stream);
    hipMemsetAsync(out, 0, (size_t)NB * ND * 4, stream);

    k_segoff<<<1, 64, 0, stream>>>(segnum, segoff);
    k_h_gemm<<<dim3(NN / 64, NA / 128), 256, 0, stream>>>(x, w1, w2, h);
    k_softmax<<<NB, 256, 0, stream>>>(h, attn, segoff);
    k_bdh<<<dim3(ND / 128, NB), 256, 0, stream>>>(x, attn, segoff, bdh, out_segment);
    k_gram<<<NB, 256, 0, stream>>>(attn, segoff, gram);
    k_post<<<dim3(ND / 128, (ND * NH) / 512), 256, 0, stream>>>(bdh, wpost, out);
}

// Round 2
// 671.497 us; speedup vs baseline: 1.8538x; 1.8538x over previous
//
#include <hip/hip_runtime.h>
#include <hip/hip_bf16.h>

// Problem dims (fixed by setup_inputs): B=64, N=16384, D=1024, A=2048, H=8
#define NB 64
#define NN 16384
#define ND 1024
#define NA 2048
#define NH 8

typedef __attribute__((ext_vector_type(4))) float f32x4;
typedef __attribute__((ext_vector_type(8))) short short8;
typedef __attribute__((ext_vector_type(8))) unsigned short ushort8;

__device__ __forceinline__ unsigned short f2bf(float f) {
    unsigned int u = __float_as_uint(f);
    u = (u + 0x7fff + ((u >> 16) & 1)) >> 16;   // round-to-nearest-even
    return (unsigned short)u;
}

__device__ __forceinline__ void load_lds16(const void* g, void* l) {
    __builtin_amdgcn_global_load_lds((const __attribute__((address_space(1))) void*)g,
                                     (__attribute__((address_space(3))) void*)l, 16, 0, 0);
}

// ---------------------------------------------------------------- seg offsets
__global__ void k_segoff(const int* __restrict__ segnum, int* __restrict__ segoff) {
    if (threadIdx.x == 0) {
        int a = 0;
        segoff[0] = 0;
        for (int b = 0; b < NB; b++) { a += segnum[b]; segoff[b + 1] = a; }
    }
}

// ------------------------------------------------------------- cast x -> bf16
__global__ __launch_bounds__(256) void k_cast_x(const float* __restrict__ x,
                                                unsigned short* __restrict__ xb) {
    size_t i = ((size_t)blockIdx.x * 256 + threadIdx.x) * 8;
    float4 a = *(const float4*)(x + i);
    float4 b = *(const float4*)(x + i + 4);
    ushort8 o;
    o[0] = f2bf(a.x); o[1] = f2bf(a.y); o[2] = f2bf(a.z); o[3] = f2bf(a.w);
    o[4] = f2bf(b.x); o[5] = f2bf(b.y); o[6] = f2bf(b.z); o[7] = f2bf(b.w);
    *(ushort8*)(xb + i) = o;
}

// ------------------------------------------- cast+transpose w1 -> bf16 [A,D]
__global__ __launch_bounds__(256) void k_cast_w1t(const float* __restrict__ w1,
                                                  unsigned short* __restrict__ w1t) {
    __shared__ unsigned short t[32][33];
    const int a0 = blockIdx.x * 32, d0 = blockIdx.y * 32;
    const int tx = threadIdx.x & 31, ty4 = (threadIdx.x >> 5) * 4;
#pragma unroll
    for (int i = 0; i < 4; i++)
        t[tx][ty4 + i] = f2bf(w1[(size_t)(d0 + ty4 + i) * NA + a0 + tx]);
    __syncthreads();
#pragma unroll
    for (int i = 0; i < 4; i++)
        w1t[(size_t)(a0 + ty4 + i) * ND + d0 + tx] = t[ty4 + i][tx];
}

// --------------------------- h = relu(x@w1)@w2 via bf16 MFMA, fused epilogue
// grid (N/128, A/128), block 256 (4 waves, 2x2 wave grid, 64x64 per wave)
__global__ __launch_bounds__(256) void k_h_mfma(const unsigned short* __restrict__ xb,
                                                const unsigned short* __restrict__ w1t,
                                                const float* __restrict__ w2,
                                                float* __restrict__ h) {
    __shared__ unsigned short As[128 * 64];  // [row][k], row stride 64 (xor-swizzled granules)
    __shared__ unsigned short Bs[128 * 64];
    __shared__ float w2s[128][NH + 1];

    const int tid = threadIdx.x;
    const int wave = tid >> 6, lane = tid & 63;
    const int wm = wave & 1, wn = wave >> 1;
    const int m0 = blockIdx.x * 128, n0 = blockIdx.y * 128;
    const int quad = lane >> 4, lc = lane & 15;

    for (int i = tid; i < 128 * NH; i += 256)
        w2s[i >> 3][i & 7] = w2[(size_t)n0 * NH + i];

    f32x4 acc[4][4];
#pragma unroll
    for (int i = 0; i < 4; i++)
#pragma unroll
        for (int j = 0; j < 4; j++) acc[i][j] = (f32x4){0.f, 0.f, 0.f, 0.f};

    const int srow = lane >> 3;           // 0..7 within issue
    const int sg = lane & 7;              // logical granule 0..7 (8 bf16 each)

    for (int k0 = 0; k0 < ND; k0 += 64) {
        __syncthreads();
#pragma unroll
        for (int i = 0; i < 4; i++) {
            int r = wave * 32 + i * 8 + srow;
            int gc = (sg ^ (r & 7)) * 8;  // swizzled global column (bf16 units)
            load_lds16(xb + (size_t)(m0 + r) * ND + k0 + gc, As + r * 64 + sg * 8);
            load_lds16(w1t + (size_t)(n0 + r) * ND + k0 + gc, Bs + r * 64 + sg * 8);
        }
        __syncthreads();
#pragma unroll
        for (int ksub = 0; ksub < 2; ksub++) {
            short8 af[4], bf[4];
            const int lg = ksub * 4 + quad;
#pragma unroll
            for (int t = 0; t < 4; t++) {
                int m = wm * 64 + t * 16 + lc;
                af[t] = *(const short8*)&As[m * 64 + (lg ^ (m & 7)) * 8];
                int n = wn * 64 + t * 16 + lc;
                bf[t] = *(const short8*)&Bs[n * 64 + (lg ^ (n & 7)) * 8];
            }
#pragma unroll
            for (int mi = 0; mi < 4; mi++)
#pragma unroll
                for (int ni = 0; ni < 4; ni++)
                    acc[mi][ni] = __builtin_amdgcn_mfma_f32_16x16x32_bf16(
                        af[mi], bf[ni], acc[mi][ni], 0, 0, 0);
        }
    }

    // epilogue: relu, * w2 chunk, reduce over the 16 lanes sharing rows, atomicAdd
#pragma unroll
    for (int mi = 0; mi < 4; mi++) {
        float ph[4][NH];
#pragma unroll
        for (int r = 0; r < 4; r++)
#pragma unroll
            for (int q = 0; q < NH; q++) ph[r][q] = 0.f;
#pragma unroll
        for (int ni = 0; ni < 4; ni++) {
            const int n = wn * 64 + ni * 16 + lc;
#pragma unroll
            for (int r = 0; r < 4; r++) {
                float v = fmaxf(acc[mi][ni][r], 0.f);
#pragma unroll
                for (int q = 0; q < NH; q++) ph[r][q] += v * w2s[n][q];
            }
        }
#pragma unroll
        for (int r = 0; r < 4; r++)
#pragma unroll
            for (int q = 0; q < NH; q++) {
                float v = ph[r][q];
                v += __shfl_xor(v, 1);
                v += __shfl_xor(v, 2);
                v += __shfl_xor(v, 4);
                v += __shfl_xor(v, 8);
                if (lc == 0)
                    atomicAdd(&h[(size_t)(m0 + wm * 64 + mi * 16 + quad * 4 + r) * NH + q], v);
            }
    }
}

// ------------------------------------------------ per-segment softmax -> attn
__global__ __launch_bounds__(256) void k_softmax(const float* __restrict__ h,
                                                 float* __restrict__ attn,
                                                 const int* __restrict__ segoff) {
    const int b = blockIdx.x;
    const int s0 = segoff[b], s1 = segoff[b + 1];
    const int tid = threadIdx.x;
    __shared__ float red[4][NH];
    __shared__ float mb[NH];
    __shared__ float sinv[NH];

    float mx[NH];
#pragma unroll
    for (int q = 0; q < NH; q++) mx[q] = -1e30f;
    for (int n = s0 + tid; n < s1; n += 256) {
        const float* hr = &h[(size_t)n * NH];
#pragma unroll
        for (int q = 0; q < NH; q++) mx[q] = fmaxf(mx[q], hr[q]);
    }
#pragma unroll
    for (int q = 0; q < NH; q++)
        for (int o = 1; o < 64; o <<= 1) mx[q] = fmaxf(mx[q], __shfl_xor(mx[q], o));
    const int wv = tid >> 6;
    if ((tid & 63) == 0)
        for (int q = 0; q < NH; q++) red[wv][q] = mx[q];
    __syncthreads();
    if (tid < NH)
        mb[tid] = fmaxf(fmaxf(red[0][tid], red[1][tid]), fmaxf(red[2][tid], red[3][tid]));
    __syncthreads();

    float sm[NH];
#pragma unroll
    for (int q = 0; q < NH; q++) sm[q] = 0.f;
    for (int n = s0 + tid; n < s1; n += 256) {
        const float* hr = &h[(size_t)n * NH];
#pragma unroll
        for (int q = 0; q < NH; q++) sm[q] += expf(hr[q] - mb[q]);
    }
#pragma unroll
    for (int q = 0; q < NH; q++)
        for (int o = 1; o < 64; o <<= 1) sm[q] += __shfl_xor(sm[q], o);
    if ((tid & 63) == 0)
        for (int q = 0; q < NH; q++) red[wv][q] = sm[q];
    __syncthreads();
    if (tid < NH)
        sinv[tid] = 1.0f / (red[0][tid] + red[1][tid] + red[2][tid] + red[3][tid]);
    __syncthreads();

    for (int n = s0 + tid; n < s1; n += 256) {
        const float* hr = &h[(size_t)n * NH];
        float* ar = &attn[(size_t)n * NH];
#pragma unroll
        for (int q = 0; q < NH; q++) ar[q] = expf(hr[q] - mb[q]) * sinv[q];
    }
}

// --------------------- out_bdh[b,d,h] = sum_n x[n,d]*attn[n,h]; + out_segment
__global__ __launch_bounds__(256) void k_bdh(const float* __restrict__ x,
                                             const float* __restrict__ attn,
                                             const int* __restrict__ segoff,
                                             float* __restrict__ bdh,
                                             float* __restrict__ out_segment) {
    const int b = blockIdx.y;
    const int d0 = blockIdx.x * 128;
    const int s0 = segoff[b], s1 = segoff[b + 1];
    const int dl = threadIdx.x & 127;
    const int d = d0 + dl;
    const int fo = threadIdx.x >> 7;

    float acc[NH];
#pragma unroll
    for (int q = 0; q < NH; q++) acc[q] = 0.f;
    float asum = 0.f;

    for (int n = s0 + fo; n < s1; n += 2) {
        float xv = x[(size_t)n * ND + d];
        const float4* ap = (const float4*)&attn[(size_t)n * NH];
        float4 a0 = ap[0], a1 = ap[1];
        acc[0] += xv * a0.x; acc[1] += xv * a0.y; acc[2] += xv * a0.z; acc[3] += xv * a0.w;
        acc[4] += xv * a1.x; acc[5] += xv * a1.y; acc[6] += xv * a1.z; acc[7] += xv * a1.w;
        asum += xv;
    }

    __shared__ float red[128][NH + 1];
    if (fo == 1) {
#pragma unroll
        for (int q = 0; q < NH; q++) red[dl][q] = acc[q];
        red[dl][NH] = asum;
    }
    __syncthreads();
    if (fo == 0) {
#pragma unroll
        for (int q = 0; q < NH; q++) acc[q] += red[dl][q];
        asum += red[dl][NH];
        float* bp = &bdh[(size_t)b * (ND * NH) + (size_t)d * NH];
#pragma unroll
        for (int q = 0; q < NH; q++) bp[q] = acc[q];
        out_segment[(size_t)b * ND + d] = asum / (float)(s1 - s0);
    }
}

// ------------------------------------------------- attn_gram[b] = attn^T@attn
__global__ __launch_bounds__(256) void k_gram(const float* __restrict__ attn,
                                              const int* __restrict__ segoff,
                                              float* __restrict__ gram) {
    const int b = blockIdx.x;
    const int s0 = segoff[b], s1 = segoff[b + 1];
    const int p = threadIdx.x & 63;
    const int g = threadIdx.x >> 6;
    const int i = p >> 3, j = p & 7;
    float acc = 0.f;
    for (int n = s0 + g; n < s1; n += 4)
        acc += attn[(size_t)n * NH + i] * attn[(size_t)n * NH + j];
    __shared__ float red[4][64];
    red[g][p] = acc;
    __syncthreads();
    if (g == 0)
        gram[(size_t)b * 64 + p] = red[0][p] + red[1][p] + red[2][p] + red[3][p];
}

// ------------------------------------- out = bdh[64,8192] @ w_post[8192,1024]
__global__ __launch_bounds__(256) void k_post(const float* __restrict__ bdh,
                                              const float* __restrict__ wp,
                                              float* __restrict__ out) {
    __shared__ float as[32][68];
    __shared__ float bs[32][128];
    const int tid = threadIdx.x;
    const int n0 = blockIdx.x * 128;
    const int k0 = blockIdx.y * 512;
    const int tr = tid >> 4, tc = tid & 15;

    float acc[4][8];
#pragma unroll
    for (int i = 0; i < 4; i++)
#pragma unroll
        for (int j = 0; j < 8; j++) acc[i][j] = 0.f;

    for (int kc = 0; kc < 512; kc += 32) {
        __syncthreads();
        {
            int r = tid >> 2;
            int c = (tid & 3) * 8;
            const float4* gp = (const float4*)(bdh + (size_t)r * (ND * NH) + k0 + kc + c);
            float4 v0 = gp[0], v1 = gp[1];
            as[c + 0][r] = v0.x; as[c + 1][r] = v0.y; as[c + 2][r] = v0.z; as[c + 3][r] = v0.w;
            as[c + 4][r] = v1.x; as[c + 5][r] = v1.y; as[c + 6][r] = v1.z; as[c + 7][r] = v1.w;
        }
        {
            int r = tid >> 3;
            int c = (tid & 7) * 16;
            const float4* gp = (const float4*)(wp + (size_t)(k0 + kc + r) * ND + n0 + c);
            float4* sp = (float4*)&bs[r][c];
            sp[0] = gp[0]; sp[1] = gp[1]; sp[2] = gp[2]; sp[3] = gp[3];
        }
        __syncthreads();
#pragma unroll
        for (int k = 0; k < 32; k++) {
            float4 a  = *(const float4*)&as[k][tr * 4];
            float4 b0 = *(const float4*)&bs[k][tc * 8];
            float4 b1 = *(const float4*)&bs[k][tc * 8 + 4];
            float av[4] = {a.x, a.y, a.z, a.w};
            float bv[8] = {b0.x, b0.y, b0.z, b0.w, b1.x, b1.y, b1.z, b1.w};
#pragma unroll
            for (int i = 0; i < 4; i++)
#pragma unroll
                for (int j = 0; j < 8; j++) acc[i][j] += av[i] * bv[j];
        }
    }

#pragma unroll
    for (int i = 0; i < 4; i++)
#pragma unroll
        for (int j = 0; j < 8; j++)
            atomicAdd(&out[(size_t)(tr * 4 + i) * ND + n0 + tc * 8 + j], acc[i][j]);
}

extern "C" void kernel_launch(void* const* d_in, const int* in_sizes, int n_in,
                              void* d_out, int out_size, void* d_ws, size_t ws_size,
                              hipStream_t stream) {
    (void)in_sizes; (void)n_in; (void)out_size; (void)ws_size;
    const float* x      = (const float*)d_in[0];
    const int*   segnum = (const int*)d_in[1];
    const float* w1     = (const float*)d_in[2];
    const float* w2     = (const float*)d_in[3];
    const float* wpost  = (const float*)d_in[4];

    float* out         = (float*)d_out;            // [64*1024]
    float* out_segment = out + NB * ND;            // [64*1024]
    float* gram        = out + 2 * NB * ND;        // [64*64]

    char* ws = (char*)d_ws;
    int*   segoff = (int*)ws;                                          // 65 ints
    float* h      = (float*)(ws + 1024);                               // N*8 f32
    float* attn   = (float*)(ws + 1024 + (size_t)NN * NH * 4);         // N*8 f32
    float* bdh    = (float*)(ws + 1024 + 2 * (size_t)NN * NH * 4);     // 64*8192 f32
    unsigned short* xb  = (unsigned short*)(ws + 4 * 1024 * 1024);     // N*D bf16 (32MB)
    unsigned short* w1t = (unsigned short*)(ws + 40 * 1024 * 1024);    // A*D bf16 (4MB)

    hipMemsetAsync(h, 0, (size_t)NN * NH * 4, stream);
    hipMemsetAsync(out, 0, (size_t)NB * ND * 4, stream);

    k_segoff<<<1, 64, 0, stream>>>(segnum, segoff);
    k_cast_x<<<(NN * ND) / (256 * 8), 256, 0, stream>>>(x, xb);
    k_cast_w1t<<<dim3(NA / 32, ND / 32), 256, 0, stream>>>(w1, w1t);
    k_h_mfma<<<dim3(NN / 128, NA / 128), 256, 0, stream>>>(xb, w1t, w2, h);
    k_softmax<<<NB, 256, 0, stream>>>(h, attn, segoff);
    k_bdh<<<dim3(ND / 128, NB), 256, 0, stream>>>(x, attn, segoff, bdh, out_segment);
    k_gram<<<NB, 256, 0, stream>>>(attn, segoff, gram);
    k_post<<<dim3(ND / 128, (ND * NH) / 512), 256, 0, stream>>>(bdh, wpost, out);
}

// Round 3
// 406.310 us; speedup vs baseline: 3.0637x; 1.6527x over previous
//
#include <hip/hip_runtime.h>
#include <hip/hip_bf16.h>

// Problem dims (fixed by setup_inputs): B=64, N=16384, D=1024, A=2048, H=8
#define NB 64
#define NN 16384
#define ND 1024
#define NA 2048
#define NH 8

typedef __attribute__((ext_vector_type(4))) float f32x4;
typedef __attribute__((ext_vector_type(8))) short short8;
typedef __attribute__((ext_vector_type(8))) unsigned short ushort8;

__device__ __forceinline__ unsigned short f2bf(float f) {
    unsigned int u = __float_as_uint(f);
    u = (u + 0x7fff + ((u >> 16) & 1)) >> 16;   // round-to-nearest-even
    return (unsigned short)u;
}

__device__ __forceinline__ float bf2f(unsigned short s) {
    return __uint_as_float((unsigned int)s << 16);
}

__device__ __forceinline__ void load_lds16(const void* g, void* l) {
    __builtin_amdgcn_global_load_lds((const __attribute__((address_space(1))) void*)g,
                                     (__attribute__((address_space(3))) void*)l, 16, 0, 0);
}

// ---------------------------------------------------------------- seg offsets
__global__ void k_segoff(const int* __restrict__ segnum, int* __restrict__ segoff) {
    if (threadIdx.x == 0) {
        int a = 0;
        segoff[0] = 0;
        for (int b = 0; b < NB; b++) { a += segnum[b]; segoff[b + 1] = a; }
    }
}

// ------------------------------------------------------------- cast x -> bf16
__global__ __launch_bounds__(256) void k_cast_x(const float* __restrict__ x,
                                                unsigned short* __restrict__ xb) {
    size_t i = ((size_t)blockIdx.x * 256 + threadIdx.x) * 8;
    float4 a = *(const float4*)(x + i);
    float4 b = *(const float4*)(x + i + 4);
    ushort8 o;
    o[0] = f2bf(a.x); o[1] = f2bf(a.y); o[2] = f2bf(a.z); o[3] = f2bf(a.w);
    o[4] = f2bf(b.x); o[5] = f2bf(b.y); o[6] = f2bf(b.z); o[7] = f2bf(b.w);
    *(ushort8*)(xb + i) = o;
}

// ------------------------------------------- cast+transpose w1 -> bf16 [A,D]
__global__ __launch_bounds__(256) void k_cast_w1t(const float* __restrict__ w1,
                                                  unsigned short* __restrict__ w1t) {
    __shared__ unsigned short t[32][33];
    const int a0 = blockIdx.x * 32, d0 = blockIdx.y * 32;
    const int tx = threadIdx.x & 31, ty4 = (threadIdx.x >> 5) * 4;
#pragma unroll
    for (int i = 0; i < 4; i++)
        t[tx][ty4 + i] = f2bf(w1[(size_t)(d0 + ty4 + i) * NA + a0 + tx]);
    __syncthreads();
#pragma unroll
    for (int i = 0; i < 4; i++)
        w1t[(size_t)(a0 + ty4 + i) * ND + d0 + tx] = t[ty4 + i][tx];
}

// ----------------------- c1 = relu(xb @ w1t^T) -> bf16 [N, A], pure MFMA GEMM
// grid (N/128, A/128), block 256 (4 waves, 2x2 wave grid, 64x64 per wave)
__global__ __launch_bounds__(256) void k_c1(const unsigned short* __restrict__ xb,
                                            const unsigned short* __restrict__ w1t,
                                            unsigned short* __restrict__ c1) {
    __shared__ unsigned short As[128 * 64];  // [row][k], row stride 64 (xor-swizzled granules)
    __shared__ unsigned short Bs[128 * 64];

    const int tid = threadIdx.x;
    const int wave = tid >> 6, lane = tid & 63;
    const int wm = wave & 1, wn = wave >> 1;
    const int m0 = blockIdx.x * 128, n0 = blockIdx.y * 128;
    const int quad = lane >> 4, lc = lane & 15;

    f32x4 acc[4][4];
#pragma unroll
    for (int i = 0; i < 4; i++)
#pragma unroll
        for (int j = 0; j < 4; j++) acc[i][j] = (f32x4){0.f, 0.f, 0.f, 0.f};

    const int srow = lane >> 3;           // 0..7 within issue
    const int sg = lane & 7;              // logical granule 0..7 (8 bf16 each)

    for (int k0 = 0; k0 < ND; k0 += 64) {
        __syncthreads();
#pragma unroll
        for (int i = 0; i < 4; i++) {
            int r = wave * 32 + i * 8 + srow;
            int gc = (sg ^ (r & 7)) * 8;  // swizzled global column (bf16 units)
            load_lds16(xb + (size_t)(m0 + r) * ND + k0 + gc, As + r * 64 + sg * 8);
            load_lds16(w1t + (size_t)(n0 + r) * ND + k0 + gc, Bs + r * 64 + sg * 8);
        }
        __syncthreads();
#pragma unroll
        for (int ksub = 0; ksub < 2; ksub++) {
            short8 af[4], bf[4];
            const int lg = ksub * 4 + quad;
#pragma unroll
            for (int t = 0; t < 4; t++) {
                int m = wm * 64 + t * 16 + lc;
                af[t] = *(const short8*)&As[m * 64 + (lg ^ (m & 7)) * 8];
                int n = wn * 64 + t * 16 + lc;
                bf[t] = *(const short8*)&Bs[n * 64 + (lg ^ (n & 7)) * 8];
            }
#pragma unroll
            for (int mi = 0; mi < 4; mi++)
#pragma unroll
                for (int ni = 0; ni < 4; ni++)
                    acc[mi][ni] = __builtin_amdgcn_mfma_f32_16x16x32_bf16(
                        af[mi], bf[ni], acc[mi][ni], 0, 0, 0);
        }
    }

    // epilogue: relu + cast + plain stores (C/D layout: col=lane&15, row=quad*4+r)
#pragma unroll
    for (int mi = 0; mi < 4; mi++)
#pragma unroll
        for (int ni = 0; ni < 4; ni++) {
            const int col = n0 + wn * 64 + ni * 16 + lc;
#pragma unroll
            for (int r = 0; r < 4; r++) {
                const int row = m0 + wm * 64 + mi * 16 + quad * 4 + r;
                c1[(size_t)row * NA + col] = f2bf(fmaxf(acc[mi][ni][r], 0.f));
            }
        }
}

// ----------------------------------- h[n,q] = sum_a c1[n,a] * w2[a,q]  (skinny)
// grid N/64 blocks, block 256: lane = row-in-group, wave = K-chunk of 512
__global__ __launch_bounds__(256) void k_h2(const unsigned short* __restrict__ c1,
                                            const float* __restrict__ w2,
                                            float* __restrict__ h) {
    const int tid = threadIdx.x;
    const int rl = tid & 63;
    const int kc = tid >> 6;
    const int row = blockIdx.x * 64 + rl;
    const unsigned short* cp = c1 + (size_t)row * NA + kc * 512;
    const float* wp = w2 + (size_t)kc * 512 * NH;

    float acc[NH];
#pragma unroll
    for (int q = 0; q < NH; q++) acc[q] = 0.f;

    for (int a = 0; a < 512; a += 8) {
        ushort8 cv = *(const ushort8*)(cp + a);
#pragma unroll
        for (int j = 0; j < 8; j++) {
            float c = bf2f(cv[j]);
            const float4* w4 = (const float4*)(wp + (size_t)(a + j) * NH);
            float4 w0 = w4[0], w1v = w4[1];   // broadcast across lanes (uniform addr)
            acc[0] += c * w0.x;  acc[1] += c * w0.y;
            acc[2] += c * w0.z;  acc[3] += c * w0.w;
            acc[4] += c * w1v.x; acc[5] += c * w1v.y;
            acc[6] += c * w1v.z; acc[7] += c * w1v.w;
        }
    }

    __shared__ float red[256][NH + 1];   // +1 pad: stride 9 floats -> conflict-free
#pragma unroll
    for (int q = 0; q < NH; q++) red[tid][q] = acc[q];
    __syncthreads();
    // 512 outputs (64 rows x 8 heads) -> 2 per thread, coalesced stores
#pragma unroll
    for (int e = 0; e < 2; e++) {
        int v = tid * 2 + e;
        int r = v >> 3, q = v & 7;
        float s = red[r][q] + red[r + 64][q] + red[r + 128][q] + red[r + 192][q];
        h[(size_t)(blockIdx.x * 64 + r) * NH + q] = s;
    }
}

// ------------------------------------------------ per-segment softmax -> attn
__global__ __launch_bounds__(256) void k_softmax(const float* __restrict__ h,
                                                 float* __restrict__ attn,
                                                 const int* __restrict__ segoff) {
    const int b = blockIdx.x;
    const int s0 = segoff[b], s1 = segoff[b + 1];
    const int tid = threadIdx.x;
    __shared__ float red[4][NH];
    __shared__ float mb[NH];
    __shared__ float sinv[NH];

    float mx[NH];
#pragma unroll
    for (int q = 0; q < NH; q++) mx[q] = -1e30f;
    for (int n = s0 + tid; n < s1; n += 256) {
        const float* hr = &h[(size_t)n * NH];
#pragma unroll
        for (int q = 0; q < NH; q++) mx[q] = fmaxf(mx[q], hr[q]);
    }
#pragma unroll
    for (int q = 0; q < NH; q++)
        for (int o = 1; o < 64; o <<= 1) mx[q] = fmaxf(mx[q], __shfl_xor(mx[q], o));
    const int wv = tid >> 6;
    if ((tid & 63) == 0)
        for (int q = 0; q < NH; q++) red[wv][q] = mx[q];
    __syncthreads();
    if (tid < NH)
        mb[tid] = fmaxf(fmaxf(red[0][tid], red[1][tid]), fmaxf(red[2][tid], red[3][tid]));
    __syncthreads();

    float sm[NH];
#pragma unroll
    for (int q = 0; q < NH; q++) sm[q] = 0.f;
    for (int n = s0 + tid; n < s1; n += 256) {
        const float* hr = &h[(size_t)n * NH];
#pragma unroll
        for (int q = 0; q < NH; q++) sm[q] += expf(hr[q] - mb[q]);
    }
#pragma unroll
    for (int q = 0; q < NH; q++)
        for (int o = 1; o < 64; o <<= 1) sm[q] += __shfl_xor(sm[q], o);
    if ((tid & 63) == 0)
        for (int q = 0; q < NH; q++) red[wv][q] = sm[q];
    __syncthreads();
    if (tid < NH)
        sinv[tid] = 1.0f / (red[0][tid] + red[1][tid] + red[2][tid] + red[3][tid]);
    __syncthreads();

    for (int n = s0 + tid; n < s1; n += 256) {
        const float* hr = &h[(size_t)n * NH];
        float* ar = &attn[(size_t)n * NH];
#pragma unroll
        for (int q = 0; q < NH; q++) ar[q] = expf(hr[q] - mb[q]) * sinv[q];
    }
}

// --------------------- out_bdh[b,d,h] = sum_n x[n,d]*attn[n,h]; + out_segment
__global__ __launch_bounds__(256) void k_bdh(const float* __restrict__ x,
                                             const float* __restrict__ attn,
                                             const int* __restrict__ segoff,
                                             float* __restrict__ bdh,
                                             float* __restrict__ out_segment) {
    const int b = blockIdx.y;
    const int d0 = blockIdx.x * 128;
    const int s0 = segoff[b], s1 = segoff[b + 1];
    const int dl = threadIdx.x & 127;
    const int d = d0 + dl;
    const int fo = threadIdx.x >> 7;

    float acc[NH];
#pragma unroll
    for (int q = 0; q < NH; q++) acc[q] = 0.f;
    float asum = 0.f;

    for (int n = s0 + fo; n < s1; n += 2) {
        float xv = x[(size_t)n * ND + d];
        const float4* ap = (const float4*)&attn[(size_t)n * NH];
        float4 a0 = ap[0], a1 = ap[1];
        acc[0] += xv * a0.x; acc[1] += xv * a0.y; acc[2] += xv * a0.z; acc[3] += xv * a0.w;
        acc[4] += xv * a1.x; acc[5] += xv * a1.y; acc[6] += xv * a1.z; acc[7] += xv * a1.w;
        asum += xv;
    }

    __shared__ float red[128][NH + 1];
    if (fo == 1) {
#pragma unroll
        for (int q = 0; q < NH; q++) red[dl][q] = acc[q];
        red[dl][NH] = asum;
    }
    __syncthreads();
    if (fo == 0) {
#pragma unroll
        for (int q = 0; q < NH; q++) acc[q] += red[dl][q];
        asum += red[dl][NH];
        float* bp = &bdh[(size_t)b * (ND * NH) + (size_t)d * NH];
#pragma unroll
        for (int q = 0; q < NH; q++) bp[q] = acc[q];
        out_segment[(size_t)b * ND + d] = asum / (float)(s1 - s0);
    }
}

// ------------------------------------------------- attn_gram[b] = attn^T@attn
__global__ __launch_bounds__(256) void k_gram(const float* __restrict__ attn,
                                              const int* __restrict__ segoff,
                                              float* __restrict__ gram) {
    const int b = blockIdx.x;
    const int s0 = segoff[b], s1 = segoff[b + 1];
    const int p = threadIdx.x & 63;
    const int g = threadIdx.x >> 6;
    const int i = p >> 3, j = p & 7;
    float acc = 0.f;
    for (int n = s0 + g; n < s1; n += 4)
        acc += attn[(size_t)n * NH + i] * attn[(size_t)n * NH + j];
    __shared__ float red[4][64];
    red[g][p] = acc;
    __syncthreads();
    if (g == 0)
        gram[(size_t)b * 64 + p] = red[0][p] + red[1][p] + red[2][p] + red[3][p];
}

// --------------- out_part[p] = bdh[64,8192] @ w_post chunk p  (no atomics)
__global__ __launch_bounds__(256) void k_post(const float* __restrict__ bdh,
                                              const float* __restrict__ wp,
                                              float* __restrict__ out_part) {
    __shared__ float as[32][68];
    __shared__ float bs[32][128];
    const int tid = threadIdx.x;
    const int n0 = blockIdx.x * 128;
    const int k0 = blockIdx.y * 512;
    const int tr = tid >> 4, tc = tid & 15;

    float acc[4][8];
#pragma unroll
    for (int i = 0; i < 4; i++)
#pragma unroll
        for (int j = 0; j < 8; j++) acc[i][j] = 0.f;

    for (int kc = 0; kc < 512; kc += 32) {
        __syncthreads();
        {
            int r = tid >> 2;
            int c = (tid & 3) * 8;
            const float4* gp = (const float4*)(bdh + (size_t)r * (ND * NH) + k0 + kc + c);
            float4 v0 = gp[0], v1 = gp[1];
            as[c + 0][r] = v0.x; as[c + 1][r] = v0.y; as[c + 2][r] = v0.z; as[c + 3][r] = v0.w;
            as[c + 4][r] = v1.x; as[c + 5][r] = v1.y; as[c + 6][r] = v1.z; as[c + 7][r] = v1.w;
        }
        {
            int r = tid >> 3;
            int c = (tid & 7) * 16;
            const float4* gp = (const float4*)(wp + (size_t)(k0 + kc + r) * ND + n0 + c);
            float4* sp = (float4*)&bs[r][c];
            sp[0] = gp[0]; sp[1] = gp[1]; sp[2] = gp[2]; sp[3] = gp[3];
        }
        __syncthreads();
#pragma unroll
        for (int k = 0; k < 32; k++) {
            float4 a  = *(const float4*)&as[k][tr * 4];
            float4 b0 = *(const float4*)&bs[k][tc * 8];
            float4 b1 = *(const float4*)&bs[k][tc * 8 + 4];
            float av[4] = {a.x, a.y, a.z, a.w};
            float bv[8] = {b0.x, b0.y, b0.z, b0.w, b1.x, b1.y, b1.z, b1.w};
#pragma unroll
            for (int i = 0; i < 4; i++)
#pragma unroll
                for (int j = 0; j < 8; j++) acc[i][j] += av[i] * bv[j];
        }
    }

    float* op = out_part + (size_t)blockIdx.y * (NB * ND);
#pragma unroll
    for (int i = 0; i < 4; i++)
#pragma unroll
        for (int j = 0; j < 8; j++)
            op[(size_t)(tr * 4 + i) * ND + n0 + tc * 8 + j] = acc[i][j];
}

// ----------------------------------------- out = sum over 16 k-chunk partials
__global__ __launch_bounds__(256) void k_post_red(const float* __restrict__ out_part,
                                                  float* __restrict__ out) {
    const int i = (blockIdx.x * 256 + threadIdx.x) * 4;
    float4 s = *(const float4*)(out_part + i);
#pragma unroll
    for (int p = 1; p < 16; p++) {
        float4 v = *(const float4*)(out_part + (size_t)p * (NB * ND) + i);
        s.x += v.x; s.y += v.y; s.z += v.z; s.w += v.w;
    }
    *(float4*)(out + i) = s;
}

extern "C" void kernel_launch(void* const* d_in, const int* in_sizes, int n_in,
                              void* d_out, int out_size, void* d_ws, size_t ws_size,
                              hipStream_t stream) {
    (void)in_sizes; (void)n_in; (void)out_size; (void)ws_size;
    const float* x      = (const float*)d_in[0];
    const int*   segnum = (const int*)d_in[1];
    const float* w1     = (const float*)d_in[2];
    const float* w2     = (const float*)d_in[3];
    const float* wpost  = (const float*)d_in[4];

    float* out         = (float*)d_out;            // [64*1024]
    float* out_segment = out + NB * ND;            // [64*1024]
    float* gram        = out + 2 * NB * ND;        // [64*64]

    char* ws = (char*)d_ws;
    // layout (needs ~108 MB of ws):
    int*   segoff   = (int*)ws;                                        // 1KB
    float* h        = (float*)(ws + (size_t)4 * 1024);                 // 512KB
    float* attn     = (float*)(ws + (size_t)1 * 1024 * 1024);          // 512KB
    float* bdh      = (float*)(ws + (size_t)2 * 1024 * 1024);          // 2MB
    float* out_part = (float*)(ws + (size_t)4 * 1024 * 1024);          // 4MB
    unsigned short* xb  = (unsigned short*)(ws + (size_t)8 * 1024 * 1024);   // 32MB
    unsigned short* w1t = (unsigned short*)(ws + (size_t)40 * 1024 * 1024);  // 4MB
    unsigned short* c1  = (unsigned short*)(ws + (size_t)44 * 1024 * 1024);  // 64MB

    k_segoff<<<1, 64, 0, stream>>>(segnum, segoff);
    k_cast_x<<<(NN * ND) / (256 * 8), 256, 0, stream>>>(x, xb);
    k_cast_w1t<<<dim3(NA / 32, ND / 32), 256, 0, stream>>>(w1, w1t);
    k_c1<<<dim3(NN / 128, NA / 128), 256, 0, stream>>>(xb, w1t, c1);
    k_h2<<<NN / 64, 256, 0, stream>>>(c1, w2, h);
    k_softmax<<<NB, 256, 0, stream>>>(h, attn, segoff);
    k_bdh<<<dim3(ND / 128, NB), 256, 0, stream>>>(x, attn, segoff, bdh, out_segment);
    k_gram<<<NB, 256, 0, stream>>>(attn, segoff, gram);
    k_post<<<dim3(ND / 128, (ND * NH) / 512), 256, 0, stream>>>(bdh, wpost, out_part);
    k_post_red<<<(NB * ND) / (256 * 4), 256, 0, stream>>>(out_part, out);
}

// Round 4
// 339.631 us; speedup vs baseline: 3.6651x; 1.1963x over previous
//
#include <hip/hip_runtime.h>
#include <hip/hip_bf16.h>

// Problem dims (fixed by setup_inputs): B=64, N=16384, D=1024, A=2048, H=8
#define NB 64
#define NN 16384
#define ND 1024
#define NA 2048
#define NH 8

typedef __attribute__((ext_vector_type(4))) float f32x4;
typedef __attribute__((ext_vector_type(8))) short short8;
typedef __attribute__((ext_vector_type(8))) unsigned short ushort8;

__device__ __forceinline__ unsigned short f2bf(float f) {
    unsigned int u = __float_as_uint(f);
    u = (u + 0x7fff + ((u >> 16) & 1)) >> 16;   // round-to-nearest-even
    return (unsigned short)u;
}

__device__ __forceinline__ float bf2f(unsigned short s) {
    return __uint_as_float((unsigned int)s << 16);
}

__device__ __forceinline__ void load_lds16(const void* g, void* l) {
    __builtin_amdgcn_global_load_lds((const __attribute__((address_space(1))) void*)g,
                                     (__attribute__((address_space(3))) void*)l, 16, 0, 0);
}

// ---------------------------------------------------------------- seg offsets
__global__ void k_segoff(const int* __restrict__ segnum, int* __restrict__ segoff) {
    if (threadIdx.x == 0) {
        int a = 0;
        segoff[0] = 0;
        for (int b = 0; b < NB; b++) { a += segnum[b]; segoff[b + 1] = a; }
    }
}

// ------------------------- combined casts: x -> xb (bf16), w1 -> w1t (bf16, [A,D])
__global__ __launch_bounds__(256) void k_cast(const float* __restrict__ x,
                                              const float* __restrict__ w1,
                                              unsigned short* __restrict__ xb,
                                              unsigned short* __restrict__ w1t) {
    __shared__ unsigned short t[32][33];
    const int bx = blockIdx.x;
    if (bx < 8192) {
        size_t i = ((size_t)bx * 256 + threadIdx.x) * 8;
        float4 a = *(const float4*)(x + i);
        float4 b = *(const float4*)(x + i + 4);
        ushort8 o;
        o[0] = f2bf(a.x); o[1] = f2bf(a.y); o[2] = f2bf(a.z); o[3] = f2bf(a.w);
        o[4] = f2bf(b.x); o[5] = f2bf(b.y); o[6] = f2bf(b.z); o[7] = f2bf(b.w);
        *(ushort8*)(xb + i) = o;
    } else {
        const int idx = bx - 8192;                 // 0..2047
        const int a0 = (idx & 63) * 32, d0 = (idx >> 6) * 32;
        const int tx = threadIdx.x & 31, ty4 = (threadIdx.x >> 5) * 4;
#pragma unroll
        for (int i = 0; i < 4; i++)
            t[tx][ty4 + i] = f2bf(w1[(size_t)(d0 + ty4 + i) * NA + a0 + tx]);
        __syncthreads();
#pragma unroll
        for (int i = 0; i < 4; i++)
            w1t[(size_t)(a0 + ty4 + i) * ND + d0 + tx] = t[ty4 + i][tx];
    }
}

// ----------------------- c1 = relu(xb @ w1t^T) -> bf16 [N, A], pure MFMA GEMM
// grid (N/128, A/128), block 256 (4 waves, 2x2 wave grid, 64x64 per wave)
__global__ __launch_bounds__(256) void k_c1(const unsigned short* __restrict__ xb,
                                            const unsigned short* __restrict__ w1t,
                                            unsigned short* __restrict__ c1) {
    __shared__ unsigned short As[128 * 64];  // [row][k], row stride 64 (xor-swizzled granules)
    __shared__ unsigned short Bs[128 * 64];

    const int tid = threadIdx.x;
    const int wave = tid >> 6, lane = tid & 63;
    const int wm = wave & 1, wn = wave >> 1;
    const int m0 = blockIdx.x * 128, n0 = blockIdx.y * 128;
    const int quad = lane >> 4, lc = lane & 15;

    f32x4 acc[4][4];
#pragma unroll
    for (int i = 0; i < 4; i++)
#pragma unroll
        for (int j = 0; j < 4; j++) acc[i][j] = (f32x4){0.f, 0.f, 0.f, 0.f};

    const int srow = lane >> 3;           // 0..7 within issue
    const int sg = lane & 7;              // logical granule 0..7 (8 bf16 each)

    for (int k0 = 0; k0 < ND; k0 += 64) {
        __syncthreads();
#pragma unroll
        for (int i = 0; i < 4; i++) {
            int r = wave * 32 + i * 8 + srow;
            int gc = (sg ^ (r & 7)) * 8;  // swizzled global column (bf16 units)
            load_lds16(xb + (size_t)(m0 + r) * ND + k0 + gc, As + r * 64 + sg * 8);
            load_lds16(w1t + (size_t)(n0 + r) * ND + k0 + gc, Bs + r * 64 + sg * 8);
        }
        __syncthreads();
#pragma unroll
        for (int ksub = 0; ksub < 2; ksub++) {
            short8 af[4], bf[4];
            const int lg = ksub * 4 + quad;
#pragma unroll
            for (int t = 0; t < 4; t++) {
                int m = wm * 64 + t * 16 + lc;
                af[t] = *(const short8*)&As[m * 64 + (lg ^ (m & 7)) * 8];
                int n = wn * 64 + t * 16 + lc;
                bf[t] = *(const short8*)&Bs[n * 64 + (lg ^ (n & 7)) * 8];
            }
#pragma unroll
            for (int mi = 0; mi < 4; mi++)
#pragma unroll
                for (int ni = 0; ni < 4; ni++)
                    acc[mi][ni] = __builtin_amdgcn_mfma_f32_16x16x32_bf16(
                        af[mi], bf[ni], acc[mi][ni], 0, 0, 0);
        }
    }

    // epilogue: relu + cast + plain stores (C/D layout: col=lane&15, row=quad*4+r)
#pragma unroll
    for (int mi = 0; mi < 4; mi++)
#pragma unroll
        for (int ni = 0; ni < 4; ni++) {
            const int col = n0 + wn * 64 + ni * 16 + lc;
#pragma unroll
            for (int r = 0; r < 4; r++) {
                const int row = m0 + wm * 64 + mi * 16 + quad * 4 + r;
                c1[(size_t)row * NA + col] = f2bf(fmaxf(acc[mi][ni][r], 0.f));
            }
        }
}

// ----------------------------------- h[n,q] = sum_a c1[n,a] * w2[a,q]  (skinny)
__global__ __launch_bounds__(256) void k_h2(const unsigned short* __restrict__ c1,
                                            const float* __restrict__ w2,
                                            float* __restrict__ h) {
    const int tid = threadIdx.x;
    const int rl = tid & 63;
    const int kc = tid >> 6;
    const int row = blockIdx.x * 64 + rl;
    const unsigned short* cp = c1 + (size_t)row * NA + kc * 512;
    const float* wp = w2 + (size_t)kc * 512 * NH;

    float acc[NH];
#pragma unroll
    for (int q = 0; q < NH; q++) acc[q] = 0.f;

    for (int a = 0; a < 512; a += 8) {
        ushort8 cv = *(const ushort8*)(cp + a);
#pragma unroll
        for (int j = 0; j < 8; j++) {
            float c = bf2f(cv[j]);
            const float4* w4 = (const float4*)(wp + (size_t)(a + j) * NH);
            float4 w0 = w4[0], w1v = w4[1];
            acc[0] += c * w0.x;  acc[1] += c * w0.y;
            acc[2] += c * w0.z;  acc[3] += c * w0.w;
            acc[4] += c * w1v.x; acc[5] += c * w1v.y;
            acc[6] += c * w1v.z; acc[7] += c * w1v.w;
        }
    }

    __shared__ float red[256][NH + 1];
#pragma unroll
    for (int q = 0; q < NH; q++) red[tid][q] = acc[q];
    __syncthreads();
#pragma unroll
    for (int e = 0; e < 2; e++) {
        int v = tid * 2 + e;
        int r = v >> 3, q = v & 7;
        float s = red[r][q] + red[r + 64][q] + red[r + 128][q] + red[r + 192][q];
        h[(size_t)(blockIdx.x * 64 + r) * NH + q] = s;
    }
}

// ------------------------------------------------ per-segment softmax -> attn
__global__ __launch_bounds__(256) void k_softmax(const float* __restrict__ h,
                                                 float* __restrict__ attn,
                                                 const int* __restrict__ segoff) {
    const int b = blockIdx.x;
    const int s0 = segoff[b], s1 = segoff[b + 1];
    const int tid = threadIdx.x;
    __shared__ float red[4][NH];
    __shared__ float mb[NH];
    __shared__ float sinv[NH];

    float mx[NH];
#pragma unroll
    for (int q = 0; q < NH; q++) mx[q] = -1e30f;
    for (int n = s0 + tid; n < s1; n += 256) {
        const float* hr = &h[(size_t)n * NH];
#pragma unroll
        for (int q = 0; q < NH; q++) mx[q] = fmaxf(mx[q], hr[q]);
    }
#pragma unroll
    for (int q = 0; q < NH; q++)
        for (int o = 1; o < 64; o <<= 1) mx[q] = fmaxf(mx[q], __shfl_xor(mx[q], o));
    const int wv = tid >> 6;
    if ((tid & 63) == 0)
        for (int q = 0; q < NH; q++) red[wv][q] = mx[q];
    __syncthreads();
    if (tid < NH)
        mb[tid] = fmaxf(fmaxf(red[0][tid], red[1][tid]), fmaxf(red[2][tid], red[3][tid]));
    __syncthreads();

    float sm[NH];
#pragma unroll
    for (int q = 0; q < NH; q++) sm[q] = 0.f;
    for (int n = s0 + tid; n < s1; n += 256) {
        const float* hr = &h[(size_t)n * NH];
#pragma unroll
        for (int q = 0; q < NH; q++) sm[q] += expf(hr[q] - mb[q]);
    }
#pragma unroll
    for (int q = 0; q < NH; q++)
        for (int o = 1; o < 64; o <<= 1) sm[q] += __shfl_xor(sm[q], o);
    if ((tid & 63) == 0)
        for (int q = 0; q < NH; q++) red[wv][q] = sm[q];
    __syncthreads();
    if (tid < NH)
        sinv[tid] = 1.0f / (red[0][tid] + red[1][tid] + red[2][tid] + red[3][tid]);
    __syncthreads();

    for (int n = s0 + tid; n < s1; n += 256) {
        const float* hr = &h[(size_t)n * NH];
        float* ar = &attn[(size_t)n * NH];
#pragma unroll
        for (int q = 0; q < NH; q++) ar[q] = expf(hr[q] - mb[q]) * sinv[q];
    }
}

// ------------------- attn_gram[b] = attn^T@attn (row/thread + wave butterfly)
__global__ __launch_bounds__(256) void k_gram(const float* __restrict__ attn,
                                              const int* __restrict__ segoff,
                                              float* __restrict__ gram) {
    const int b = blockIdx.x;
    const int s0 = segoff[b], s1 = segoff[b + 1];
    const int tid = threadIdx.x;
    float g[NH][NH];
#pragma unroll
    for (int i = 0; i < NH; i++)
#pragma unroll
        for (int j = 0; j < NH; j++) g[i][j] = 0.f;

    for (int n = s0 + tid; n < s1; n += 256) {
        const float4* ap = (const float4*)&attn[(size_t)n * NH];
        float4 a0 = ap[0], a1 = ap[1];
        float a[NH] = {a0.x, a0.y, a0.z, a0.w, a1.x, a1.y, a1.z, a1.w};
#pragma unroll
        for (int i = 0; i < NH; i++)
#pragma unroll
            for (int j = 0; j < NH; j++) g[i][j] += a[i] * a[j];
    }
#pragma unroll
    for (int i = 0; i < NH; i++)
#pragma unroll
        for (int j = 0; j < NH; j++)
            for (int o = 1; o < 64; o <<= 1) g[i][j] += __shfl_xor(g[i][j], o);

    __shared__ float red[4][64];
    if ((tid & 63) == 0) {
#pragma unroll
        for (int i = 0; i < NH; i++)
#pragma unroll
            for (int j = 0; j < NH; j++) red[tid >> 6][i * NH + j] = g[i][j];
    }
    __syncthreads();
    if (tid < 64)
        gram[(size_t)b * 64 + tid] = red[0][tid] + red[1][tid] + red[2][tid] + red[3][tid];
}

// ---- bdh_part[slot][b][d][h] partial of sum_n x[n,d]*attn[n,h]; + xsum partial
// grid (8 slots, 64 segs), block 128: thread owns 8 d-cols (ushort8 load/frame)
__global__ __launch_bounds__(128) void k_bdh(const unsigned short* __restrict__ xb,
                                             const float* __restrict__ attn,
                                             const int* __restrict__ segoff,
                                             float* __restrict__ bdh_part,
                                             float* __restrict__ xsum_part) {
    const int slot = blockIdx.x;          // 0..7
    const int b = blockIdx.y;
    const int s0 = segoff[b], s1 = segoff[b + 1];
    const int dl = threadIdx.x;           // 0..127 -> d = dl*8..dl*8+7

    float acc[8][NH];
    float xs[8];
#pragma unroll
    for (int dd = 0; dd < 8; dd++) {
        xs[dd] = 0.f;
#pragma unroll
        for (int q = 0; q < NH; q++) acc[dd][q] = 0.f;
    }

    for (int n = s0 + slot; n < s1; n += 8) {
        ushort8 xv = *(const ushort8*)(xb + (size_t)n * ND + dl * 8);
        const float4* ap = (const float4*)&attn[(size_t)n * NH];
        float4 a0 = ap[0], a1 = ap[1];
        float aq[NH] = {a0.x, a0.y, a0.z, a0.w, a1.x, a1.y, a1.z, a1.w};
#pragma unroll
        for (int dd = 0; dd < 8; dd++) {
            float xf = bf2f(xv[dd]);
            xs[dd] += xf;
#pragma unroll
            for (int q = 0; q < NH; q++) acc[dd][q] += xf * aq[q];
        }
    }

    float* bp = bdh_part + ((size_t)slot * NB + b) * (ND * NH) + (size_t)dl * 64;
#pragma unroll
    for (int dd = 0; dd < 8; dd++) {
        *(float4*)(bp + dd * 8)     = make_float4(acc[dd][0], acc[dd][1], acc[dd][2], acc[dd][3]);
        *(float4*)(bp + dd * 8 + 4) = make_float4(acc[dd][4], acc[dd][5], acc[dd][6], acc[dd][7]);
    }
    float* xp = xsum_part + ((size_t)slot * NB + b) * ND + (size_t)dl * 8;
    *(float4*)(xp)     = make_float4(xs[0], xs[1], xs[2], xs[3]);
    *(float4*)(xp + 4) = make_float4(xs[4], xs[5], xs[6], xs[7]);
}

// ---------------- reduce 8 slots -> bdh fp32 [64][8192]; out_segment = mean(x)
__global__ __launch_bounds__(256) void k_bdh_red(const float* __restrict__ bdh_part,
                                                 const float* __restrict__ xsum_part,
                                                 const int* __restrict__ segoff,
                                                 float* __restrict__ bdh,
                                                 float* __restrict__ out_segment) {
    const int gid = blockIdx.x * 256 + threadIdx.x;   // 0..65535
    const int b = gid >> 10, d = gid & 1023;
    float4 sa = make_float4(0.f, 0.f, 0.f, 0.f);
    float4 sb = make_float4(0.f, 0.f, 0.f, 0.f);
    float xsum = 0.f;
#pragma unroll
    for (int s = 0; s < 8; s++) {
        const float* p = bdh_part + ((size_t)s * NB + b) * (ND * NH) + (size_t)d * NH;
        float4 u = ((const float4*)p)[0], v = ((const float4*)p)[1];
        sa.x += u.x; sa.y += u.y; sa.z += u.z; sa.w += u.w;
        sb.x += v.x; sb.y += v.y; sb.z += v.z; sb.w += v.w;
        xsum += xsum_part[((size_t)s * NB + b) * ND + d];
    }
    float* bp = bdh + (size_t)b * (ND * NH) + (size_t)d * NH;
    ((float4*)bp)[0] = sa;
    ((float4*)bp)[1] = sb;
    const int len = segoff[b + 1] - segoff[b];
    out_segment[(size_t)b * ND + d] = xsum / (float)len;
}

// --------------- out_part[p] = bdh[64,8192] @ w_post chunk p  (split-K 32)
__global__ __launch_bounds__(256) void k_post(const float* __restrict__ bdh,
                                              const float* __restrict__ wp,
                                              float* __restrict__ out_part) {
    __shared__ float as[32][68];
    __shared__ float bs[32][128];
    const int tid = threadIdx.x;
    const int n0 = blockIdx.x * 128;
    const int k0 = blockIdx.y * 256;
    const int tr = tid >> 4, tc = tid & 15;

    float acc[4][8];
#pragma unroll
    for (int i = 0; i < 4; i++)
#pragma unroll
        for (int j = 0; j < 8; j++) acc[i][j] = 0.f;

    for (int kc = 0; kc < 256; kc += 32) {
        __syncthreads();
        {
            int r = tid >> 2;
            int c = (tid & 3) * 8;
            const float4* gp = (const float4*)(bdh + (size_t)r * (ND * NH) + k0 + kc + c);
            float4 v0 = gp[0], v1 = gp[1];
            as[c + 0][r] = v0.x; as[c + 1][r] = v0.y; as[c + 2][r] = v0.z; as[c + 3][r] = v0.w;
            as[c + 4][r] = v1.x; as[c + 5][r] = v1.y; as[c + 6][r] = v1.z; as[c + 7][r] = v1.w;
        }
        {
            int r = tid >> 3;
            int c = (tid & 7) * 16;
            const float4* gp = (const float4*)(wp + (size_t)(k0 + kc + r) * ND + n0 + c);
            float4* sp = (float4*)&bs[r][c];
            sp[0] = gp[0]; sp[1] = gp[1]; sp[2] = gp[2]; sp[3] = gp[3];
        }
        __syncthreads();
#pragma unroll
        for (int k = 0; k < 32; k++) {
            float4 a  = *(const float4*)&as[k][tr * 4];
            float4 b0 = *(const float4*)&bs[k][tc * 8];
            float4 b1 = *(const float4*)&bs[k][tc * 8 + 4];
            float av[4] = {a.x, a.y, a.z, a.w};
            float bv[8] = {b0.x, b0.y, b0.z, b0.w, b1.x, b1.y, b1.z, b1.w};
#pragma unroll
            for (int i = 0; i < 4; i++)
#pragma unroll
                for (int j = 0; j < 8; j++) acc[i][j] += av[i] * bv[j];
        }
    }

    float* op = out_part + (size_t)blockIdx.y * (NB * ND);
#pragma unroll
    for (int i = 0; i < 4; i++)
#pragma unroll
        for (int j = 0; j < 8; j++)
            op[(size_t)(tr * 4 + i) * ND + n0 + tc * 8 + j] = acc[i][j];
}

// ----------------------------------------- out = sum over 32 k-chunk partials
__global__ __launch_bounds__(256) void k_post_red(const float* __restrict__ out_part,
                                                  float* __restrict__ out) {
    const int i = (blockIdx.x * 256 + threadIdx.x) * 4;
    float4 s = *(const float4*)(out_part + i);
#pragma unroll
    for (int p = 1; p < 32; p++) {
        float4 v = *(const float4*)(out_part + (size_t)p * (NB * ND) + i);
        s.x += v.x; s.y += v.y; s.z += v.z; s.w += v.w;
    }
    *(float4*)(out + i) = s;
}

extern "C" void kernel_launch(void* const* d_in, const int* in_sizes, int n_in,
                              void* d_out, int out_size, void* d_ws, size_t ws_size,
                              hipStream_t stream) {
    (void)in_sizes; (void)n_in; (void)out_size; (void)ws_size;
    const float* x      = (const float*)d_in[0];
    const int*   segnum = (const int*)d_in[1];
    const float* w1     = (const float*)d_in[2];
    const float* w2     = (const float*)d_in[3];
    const float* wpost  = (const float*)d_in[4];

    float* out         = (float*)d_out;            // [64*1024]
    float* out_segment = out + NB * ND;            // [64*1024]
    float* gram        = out + 2 * NB * ND;        // [64*64]

    char* ws = (char*)d_ws;
    // layout (peak 104 MB; partials alias the dead c1 region):
    int*   segoff   = (int*)ws;                                         // 1KB  @0
    float* h        = (float*)(ws + (size_t)4 * 1024);                  // 512KB @4KB
    float* attn     = (float*)(ws + (size_t)1 * 1024 * 1024);           // 512KB @1MB
    float* bdh      = (float*)(ws + (size_t)2 * 1024 * 1024);           // 2MB  @2MB
    unsigned short* xb  = (unsigned short*)(ws + (size_t)4 * 1024 * 1024);   // 32MB @4MB
    unsigned short* w1t = (unsigned short*)(ws + (size_t)36 * 1024 * 1024);  // 4MB  @36MB
    unsigned short* c1  = (unsigned short*)(ws + (size_t)40 * 1024 * 1024);  // 64MB @40MB
    // aliased into c1's region (written only after k_h2, the last c1 reader):
    float* bdh_part = (float*)(ws + (size_t)40 * 1024 * 1024);          // 16MB @40MB
    float* xsum_part= (float*)(ws + (size_t)56 * 1024 * 1024);          // 2MB  @56MB
    float* out_part = (float*)(ws + (size_t)58 * 1024 * 1024);          // 8MB  @58MB

    k_segoff<<<1, 64, 0, stream>>>(segnum, segoff);
    k_cast<<<8192 + 2048, 256, 0, stream>>>(x, w1, xb, w1t);
    k_c1<<<dim3(NN / 128, NA / 128), 256, 0, stream>>>(xb, w1t, c1);
    k_h2<<<NN / 64, 256, 0, stream>>>(c1, w2, h);
    k_softmax<<<NB, 256, 0, stream>>>(h, attn, segoff);
    k_gram<<<NB, 256, 0, stream>>>(attn, segoff, gram);
    k_bdh<<<dim3(8, NB), 128, 0, stream>>>(xb, attn, segoff, bdh_part, xsum_part);
    k_bdh_red<<<256, 256, 0, stream>>>(bdh_part, xsum_part, segoff, bdh, out_segment);
    k_post<<<dim3(ND / 128, 32), 256, 0, stream>>>(bdh, wpost, out_part);
    k_post_red<<<(NB * ND) / (256 * 4), 256, 0, stream>>>(out_part, out);
}

// Round 5
// 320.692 us; speedup vs baseline: 3.8816x; 1.0591x over previous
//
#include <hip/hip_runtime.h>
#include <hip/hip_bf16.h>

// Problem dims (fixed by setup_inputs): B=64, N=16384, D=1024, A=2048, H=8
#define NB 64
#define NN 16384
#define ND 1024
#define NA 2048
#define NH 8
#define NSLOT 16    // k_bdh frame-offset slots
#define KSPL 64     // k_post split-K chunks

typedef __attribute__((ext_vector_type(4))) float f32x4;
typedef __attribute__((ext_vector_type(8))) short short8;
typedef __attribute__((ext_vector_type(8))) unsigned short ushort8;

__device__ __forceinline__ unsigned short f2bf(float f) {
    unsigned int u = __float_as_uint(f);
    u = (u + 0x7fff + ((u >> 16) & 1)) >> 16;   // round-to-nearest-even
    return (unsigned short)u;
}

__device__ __forceinline__ float bf2f(unsigned short s) {
    return __uint_as_float((unsigned int)s << 16);
}

__device__ __forceinline__ void load_lds16(const void* g, void* l) {
    __builtin_amdgcn_global_load_lds((const __attribute__((address_space(1))) void*)g,
                                     (__attribute__((address_space(3))) void*)l, 16, 0, 0);
}

// ---- k_pre: segoff + cast x->xb + cast/transpose w1->w1t + w2 -> bf16 hi/lo planes
__global__ __launch_bounds__(256) void k_pre(const float* __restrict__ x,
                                             const float* __restrict__ w1,
                                             const float* __restrict__ w2,
                                             const int* __restrict__ segnum,
                                             unsigned short* __restrict__ xb,
                                             unsigned short* __restrict__ w1t,
                                             unsigned short* __restrict__ w2t_hi,
                                             unsigned short* __restrict__ w2t_lo,
                                             int* __restrict__ segoff) {
    __shared__ unsigned short t[32][33];
    const int bx = blockIdx.x;
    if (bx < 8192) {
        size_t i = ((size_t)bx * 256 + threadIdx.x) * 8;
        float4 a = *(const float4*)(x + i);
        float4 b = *(const float4*)(x + i + 4);
        ushort8 o;
        o[0] = f2bf(a.x); o[1] = f2bf(a.y); o[2] = f2bf(a.z); o[3] = f2bf(a.w);
        o[4] = f2bf(b.x); o[5] = f2bf(b.y); o[6] = f2bf(b.z); o[7] = f2bf(b.w);
        *(ushort8*)(xb + i) = o;
    } else if (bx < 10240) {
        const int idx = bx - 8192;                 // 0..2047
        const int a0 = (idx & 63) * 32, d0 = (idx >> 6) * 32;
        const int tx = threadIdx.x & 31, ty4 = (threadIdx.x >> 5) * 4;
#pragma unroll
        for (int i = 0; i < 4; i++)
            t[tx][ty4 + i] = f2bf(w1[(size_t)(d0 + ty4 + i) * NA + a0 + tx]);
        __syncthreads();
#pragma unroll
        for (int i = 0; i < 4; i++)
            w1t[(size_t)(a0 + ty4 + i) * ND + d0 + tx] = t[ty4 + i][tx];
    } else {
        // w2 [2048][8] -> w2t_{hi,lo} [16][2048] (rows 8..15 zero)
        for (int i = threadIdx.x; i < NA * NH; i += 256) {
            int a = i >> 3, q = i & 7;
            float w = w2[i];
            unsigned short hi = f2bf(w);
            float r = w - bf2f(hi);
            w2t_hi[(size_t)q * NA + a] = hi;
            w2t_lo[(size_t)q * NA + a] = f2bf(r);
        }
        for (int i = threadIdx.x; i < NA * NH; i += 256) {
            w2t_hi[NA * NH + i] = 0;
            w2t_lo[NA * NH + i] = 0;
        }
        if (threadIdx.x == 0) {
            int a = 0;
            segoff[0] = 0;
            for (int b = 0; b < NB; b++) { a += segnum[b]; segoff[b + 1] = a; }
        }
    }
}

// ----------------------- c1 = relu(xb @ w1t^T) -> bf16 [N, A], pure MFMA GEMM
// grid (N/128, A/128), block 256 (4 waves, 2x2 wave grid, 64x64 per wave)
__global__ __launch_bounds__(256) void k_c1(const unsigned short* __restrict__ xb,
                                            const unsigned short* __restrict__ w1t,
                                            unsigned short* __restrict__ c1) {
    __shared__ unsigned short As[128 * 64];  // [row][k], row stride 64 (xor-swizzled granules)
    __shared__ unsigned short Bs[128 * 64];

    const int tid = threadIdx.x;
    const int wave = tid >> 6, lane = tid & 63;
    const int wm = wave & 1, wn = wave >> 1;
    const int m0 = blockIdx.x * 128, n0 = blockIdx.y * 128;
    const int quad = lane >> 4, lc = lane & 15;

    f32x4 acc[4][4];
#pragma unroll
    for (int i = 0; i < 4; i++)
#pragma unroll
        for (int j = 0; j < 4; j++) acc[i][j] = (f32x4){0.f, 0.f, 0.f, 0.f};

    const int srow = lane >> 3;           // 0..7 within issue
    const int sg = lane & 7;              // logical granule 0..7 (8 bf16 each)

    for (int k0 = 0; k0 < ND; k0 += 64) {
        __syncthreads();
#pragma unroll
        for (int i = 0; i < 4; i++) {
            int r = wave * 32 + i * 8 + srow;
            int gc = (sg ^ (r & 7)) * 8;  // swizzled global column (bf16 units)
            load_lds16(xb + (size_t)(m0 + r) * ND + k0 + gc, As + r * 64 + sg * 8);
            load_lds16(w1t + (size_t)(n0 + r) * ND + k0 + gc, Bs + r * 64 + sg * 8);
        }
        __syncthreads();
#pragma unroll
        for (int ksub = 0; ksub < 2; ksub++) {
            short8 af[4], bf[4];
            const int lg = ksub * 4 + quad;
#pragma unroll
            for (int t = 0; t < 4; t++) {
                int m = wm * 64 + t * 16 + lc;
                af[t] = *(const short8*)&As[m * 64 + (lg ^ (m & 7)) * 8];
                int n = wn * 64 + t * 16 + lc;
                bf[t] = *(const short8*)&Bs[n * 64 + (lg ^ (n & 7)) * 8];
            }
#pragma unroll
            for (int mi = 0; mi < 4; mi++)
#pragma unroll
                for (int ni = 0; ni < 4; ni++)
                    acc[mi][ni] = __builtin_amdgcn_mfma_f32_16x16x32_bf16(
                        af[mi], bf[ni], acc[mi][ni], 0, 0, 0);
        }
    }

    // epilogue: relu + cast + plain stores (C/D layout: col=lane&15, row=quad*4+r)
#pragma unroll
    for (int mi = 0; mi < 4; mi++)
#pragma unroll
        for (int ni = 0; ni < 4; ni++) {
            const int col = n0 + wn * 64 + ni * 16 + lc;
#pragma unroll
            for (int r = 0; r < 4; r++) {
                const int row = m0 + wm * 64 + mi * 16 + quad * 4 + r;
                c1[(size_t)row * NA + col] = f2bf(fmaxf(acc[mi][ni][r], 0.f));
            }
        }
}

// -------- h = c1 @ w2 via MFMA, register-only: wave owns 16 rows, w2 as hi+lo
// grid 256 blocks x 4 waves = 1024 row-groups of 16
__global__ __launch_bounds__(256) void k_h2m(const unsigned short* __restrict__ c1,
                                             const unsigned short* __restrict__ w2t_hi,
                                             const unsigned short* __restrict__ w2t_lo,
                                             float* __restrict__ h) {
    const int wave = threadIdx.x >> 6, lane = threadIdx.x & 63;
    const int quad = lane >> 4, lc = lane & 15;
    const int row0 = (blockIdx.x * 4 + wave) * 16;

    f32x4 acc = (f32x4){0.f, 0.f, 0.f, 0.f};
    const unsigned short* ap  = c1 + (size_t)(row0 + lc) * NA + quad * 8;
    const unsigned short* bhp = w2t_hi + (size_t)lc * NA + quad * 8;
    const unsigned short* blp = w2t_lo + (size_t)lc * NA + quad * 8;

#pragma unroll 4
    for (int kc = 0; kc < NA; kc += 32) {
        short8 af = *(const short8*)(ap + kc);
        short8 bh = *(const short8*)(bhp + kc);
        short8 bl = *(const short8*)(blp + kc);
        acc = __builtin_amdgcn_mfma_f32_16x16x32_bf16(af, bh, acc, 0, 0, 0);
        acc = __builtin_amdgcn_mfma_f32_16x16x32_bf16(af, bl, acc, 0, 0, 0);
    }

    if (lc < NH) {
#pragma unroll
        for (int r = 0; r < 4; r++)
            h[(size_t)(row0 + quad * 4 + r) * NH + lc] = acc[r];
    }
}

// --------------- per-segment softmax -> attn, with gram fused into pass 3
__global__ __launch_bounds__(256) void k_attn(const float* __restrict__ h,
                                              float* __restrict__ attn,
                                              const int* __restrict__ segoff,
                                              float* __restrict__ gram) {
    const int b = blockIdx.x;
    const int s0 = segoff[b], s1 = segoff[b + 1];
    const int tid = threadIdx.x;
    __shared__ float red[4][NH];
    __shared__ float mb[NH];
    __shared__ float sinv[NH];

    float mx[NH];
#pragma unroll
    for (int q = 0; q < NH; q++) mx[q] = -1e30f;
    for (int n = s0 + tid; n < s1; n += 256) {
        const float* hr = &h[(size_t)n * NH];
#pragma unroll
        for (int q = 0; q < NH; q++) mx[q] = fmaxf(mx[q], hr[q]);
    }
#pragma unroll
    for (int q = 0; q < NH; q++)
        for (int o = 1; o < 64; o <<= 1) mx[q] = fmaxf(mx[q], __shfl_xor(mx[q], o));
    const int wv = tid >> 6;
    if ((tid & 63) == 0)
        for (int q = 0; q < NH; q++) red[wv][q] = mx[q];
    __syncthreads();
    if (tid < NH)
        mb[tid] = fmaxf(fmaxf(red[0][tid], red[1][tid]), fmaxf(red[2][tid], red[3][tid]));
    __syncthreads();

    float sm[NH];
#pragma unroll
    for (int q = 0; q < NH; q++) sm[q] = 0.f;
    for (int n = s0 + tid; n < s1; n += 256) {
        const float* hr = &h[(size_t)n * NH];
#pragma unroll
        for (int q = 0; q < NH; q++) sm[q] += expf(hr[q] - mb[q]);
    }
#pragma unroll
    for (int q = 0; q < NH; q++)
        for (int o = 1; o < 64; o <<= 1) sm[q] += __shfl_xor(sm[q], o);
    if ((tid & 63) == 0)
        for (int q = 0; q < NH; q++) red[wv][q] = sm[q];
    __syncthreads();
    if (tid < NH)
        sinv[tid] = 1.0f / (red[0][tid] + red[1][tid] + red[2][tid] + red[3][tid]);
    __syncthreads();

    float g[NH][NH];
#pragma unroll
    for (int i = 0; i < NH; i++)
#pragma unroll
        for (int j = 0; j < NH; j++) g[i][j] = 0.f;

    for (int n = s0 + tid; n < s1; n += 256) {
        const float* hr = &h[(size_t)n * NH];
        float* ar = &attn[(size_t)n * NH];
        float a[NH];
#pragma unroll
        for (int q = 0; q < NH; q++) { a[q] = expf(hr[q] - mb[q]) * sinv[q]; ar[q] = a[q]; }
#pragma unroll
        for (int i = 0; i < NH; i++)
#pragma unroll
            for (int j = 0; j < NH; j++) g[i][j] += a[i] * a[j];
    }
#pragma unroll
    for (int i = 0; i < NH; i++)
#pragma unroll
        for (int j = 0; j < NH; j++)
            for (int o = 1; o < 64; o <<= 1) g[i][j] += __shfl_xor(g[i][j], o);

    __shared__ float gred[4][64];
    if ((tid & 63) == 0) {
#pragma unroll
        for (int i = 0; i < NH; i++)
#pragma unroll
            for (int j = 0; j < NH; j++) gred[wv][i * NH + j] = g[i][j];
    }
    __syncthreads();
    if (tid < 64)
        gram[(size_t)b * 64 + tid] = gred[0][tid] + gred[1][tid] + gred[2][tid] + gred[3][tid];
}

// ---- bdh_part[slot][b][d][h] partial of sum_n x[n,d]*attn[n,h]; + xsum partial
// grid (NSLOT slots, 64 segs), block 128: thread owns 8 d-cols (ushort8/frame)
__global__ __launch_bounds__(128) void k_bdh(const unsigned short* __restrict__ xb,
                                             const float* __restrict__ attn,
                                             const int* __restrict__ segoff,
                                             float* __restrict__ bdh_part,
                                             float* __restrict__ xsum_part) {
    const int slot = blockIdx.x;          // 0..NSLOT-1
    const int b = blockIdx.y;
    const int s0 = segoff[b], s1 = segoff[b + 1];
    const int dl = threadIdx.x;           // 0..127 -> d = dl*8..dl*8+7

    float acc[8][NH];
    float xs[8];
#pragma unroll
    for (int dd = 0; dd < 8; dd++) {
        xs[dd] = 0.f;
#pragma unroll
        for (int q = 0; q < NH; q++) acc[dd][q] = 0.f;
    }

    for (int n = s0 + slot; n < s1; n += NSLOT) {
        ushort8 xv = *(const ushort8*)(xb + (size_t)n * ND + dl * 8);
        const float4* ap = (const float4*)&attn[(size_t)n * NH];
        float4 a0 = ap[0], a1 = ap[1];
        float aq[NH] = {a0.x, a0.y, a0.z, a0.w, a1.x, a1.y, a1.z, a1.w};
#pragma unroll
        for (int dd = 0; dd < 8; dd++) {
            float xf = bf2f(xv[dd]);
            xs[dd] += xf;
#pragma unroll
            for (int q = 0; q < NH; q++) acc[dd][q] += xf * aq[q];
        }
    }

    float* bp = bdh_part + ((size_t)slot * NB + b) * (ND * NH) + (size_t)dl * 64;
#pragma unroll
    for (int dd = 0; dd < 8; dd++) {
        *(float4*)(bp + dd * 8)     = make_float4(acc[dd][0], acc[dd][1], acc[dd][2], acc[dd][3]);
        *(float4*)(bp + dd * 8 + 4) = make_float4(acc[dd][4], acc[dd][5], acc[dd][6], acc[dd][7]);
    }
    float* xp = xsum_part + ((size_t)slot * NB + b) * ND + (size_t)dl * 8;
    *(float4*)(xp)     = make_float4(xs[0], xs[1], xs[2], xs[3]);
    *(float4*)(xp + 4) = make_float4(xs[4], xs[5], xs[6], xs[7]);
}

// ------------- reduce NSLOT slots -> bdh fp32 [64][8192]; out_segment = mean(x)
__global__ __launch_bounds__(256) void k_bdh_red(const float* __restrict__ bdh_part,
                                                 const float* __restrict__ xsum_part,
                                                 const int* __restrict__ segoff,
                                                 float* __restrict__ bdh,
                                                 float* __restrict__ out_segment) {
    const int gid = blockIdx.x * 256 + threadIdx.x;   // 0..65535
    const int b = gid >> 10, d = gid & 1023;
    float4 sa = make_float4(0.f, 0.f, 0.f, 0.f);
    float4 sb = make_float4(0.f, 0.f, 0.f, 0.f);
    float xsum = 0.f;
#pragma unroll
    for (int s = 0; s < NSLOT; s++) {
        const float* p = bdh_part + ((size_t)s * NB + b) * (ND * NH) + (size_t)d * NH;
        float4 u = ((const float4*)p)[0], v = ((const float4*)p)[1];
        sa.x += u.x; sa.y += u.y; sa.z += u.z; sa.w += u.w;
        sb.x += v.x; sb.y += v.y; sb.z += v.z; sb.w += v.w;
        xsum += xsum_part[((size_t)s * NB + b) * ND + d];
    }
    float* bp = bdh + (size_t)b * (ND * NH) + (size_t)d * NH;
    ((float4*)bp)[0] = sa;
    ((float4*)bp)[1] = sb;
    const int len = segoff[b + 1] - segoff[b];
    out_segment[(size_t)b * ND + d] = xsum / (float)len;
}

// --------------- out_part[p] = bdh[64,8192] @ w_post chunk p  (split-K KSPL)
__global__ __launch_bounds__(256) void k_post(const float* __restrict__ bdh,
                                              const float* __restrict__ wp,
                                              float* __restrict__ out_part) {
    __shared__ float as[32][68];
    __shared__ float bs[32][128];
    const int tid = threadIdx.x;
    const int n0 = blockIdx.x * 128;
    const int k0 = blockIdx.y * (8192 / KSPL);
    const int tr = tid >> 4, tc = tid & 15;

    float acc[4][8];
#pragma unroll
    for (int i = 0; i < 4; i++)
#pragma unroll
        for (int j = 0; j < 8; j++) acc[i][j] = 0.f;

    for (int kc = 0; kc < 8192 / KSPL; kc += 32) {
        __syncthreads();
        {
            int r = tid >> 2;
            int c = (tid & 3) * 8;
            const float4* gp = (const float4*)(bdh + (size_t)r * (ND * NH) + k0 + kc + c);
            float4 v0 = gp[0], v1 = gp[1];
            as[c + 0][r] = v0.x; as[c + 1][r] = v0.y; as[c + 2][r] = v0.z; as[c + 3][r] = v0.w;
            as[c + 4][r] = v1.x; as[c + 5][r] = v1.y; as[c + 6][r] = v1.z; as[c + 7][r] = v1.w;
        }
        {
            int r = tid >> 3;
            int c = (tid & 7) * 16;
            const float4* gp = (const float4*)(wp + (size_t)(k0 + kc + r) * ND + n0 + c);
            float4* sp = (float4*)&bs[r][c];
            sp[0] = gp[0]; sp[1] = gp[1]; sp[2] = gp[2]; sp[3] = gp[3];
        }
        __syncthreads();
#pragma unroll
        for (int k = 0; k < 32; k++) {
            float4 a  = *(const float4*)&as[k][tr * 4];
            float4 b0 = *(const float4*)&bs[k][tc * 8];
            float4 b1 = *(const float4*)&bs[k][tc * 8 + 4];
            float av[4] = {a.x, a.y, a.z, a.w};
            float bv[8] = {b0.x, b0.y, b0.z, b0.w, b1.x, b1.y, b1.z, b1.w};
#pragma unroll
            for (int i = 0; i < 4; i++)
#pragma unroll
                for (int j = 0; j < 8; j++) acc[i][j] += av[i] * bv[j];
        }
    }

    float* op = out_part + (size_t)blockIdx.y * (NB * ND);
#pragma unroll
    for (int i = 0; i < 4; i++)
#pragma unroll
        for (int j = 0; j < 8; j++)
            op[(size_t)(tr * 4 + i) * ND + n0 + tc * 8 + j] = acc[i][j];
}

// ------------------------------------- out = sum over KSPL k-chunk partials
__global__ __launch_bounds__(256) void k_post_red(const float* __restrict__ out_part,
                                                  float* __restrict__ out) {
    const int i = (blockIdx.x * 256 + threadIdx.x) * 4;
    float4 s = *(const float4*)(out_part + i);
#pragma unroll
    for (int p = 1; p < KSPL; p++) {
        float4 v = *(const float4*)(out_part + (size_t)p * (NB * ND) + i);
        s.x += v.x; s.y += v.y; s.z += v.z; s.w += v.w;
    }
    *(float4*)(out + i) = s;
}

extern "C" void kernel_launch(void* const* d_in, const int* in_sizes, int n_in,
                              void* d_out, int out_size, void* d_ws, size_t ws_size,
                              hipStream_t stream) {
    (void)in_sizes; (void)n_in; (void)out_size; (void)ws_size;
    const float* x      = (const float*)d_in[0];
    const int*   segnum = (const int*)d_in[1];
    const float* w1     = (const float*)d_in[2];
    const float* w2     = (const float*)d_in[3];
    const float* wpost  = (const float*)d_in[4];

    float* out         = (float*)d_out;            // [64*1024]
    float* out_segment = out + NB * ND;            // [64*1024]
    float* gram        = out + 2 * NB * ND;        // [64*64]

    char* ws = (char*)d_ws;
    const size_t MB = 1024 * 1024;
    // layout (peak 105 MB; partials alias the dead c1 region):
    int*   segoff   = (int*)ws;                                    // 1KB   @0
    float* h        = (float*)(ws + 4 * 1024);                     // 512KB @4KB
    float* attn     = (float*)(ws + 1 * MB);                       // 512KB @1MB
    float* bdh      = (float*)(ws + 2 * MB);                       // 2MB   @2MB
    unsigned short* w2t_hi = (unsigned short*)(ws + 4 * MB);       // 64KB  @4MB
    unsigned short* w2t_lo = (unsigned short*)(ws + 4 * MB + 64 * 1024); // 64KB
    unsigned short* xb  = (unsigned short*)(ws + 5 * MB);          // 32MB  @5MB
    unsigned short* w1t = (unsigned short*)(ws + 37 * MB);         // 4MB   @37MB
    unsigned short* c1  = (unsigned short*)(ws + 41 * MB);         // 64MB  @41MB
    // aliased into c1's region (written only after k_h2m, the last c1 reader):
    float* bdh_part  = (float*)(ws + 41 * MB);                     // 32MB  @41MB
    float* xsum_part = (float*)(ws + 73 * MB);                     // 4MB   @73MB
    float* out_part  = (float*)(ws + 77 * MB);                     // 16MB  @77MB

    k_pre<<<10241, 256, 0, stream>>>(x, w1, w2, segnum, xb, w1t, w2t_hi, w2t_lo, segoff);
    k_c1<<<dim3(NN / 128, NA / 128), 256, 0, stream>>>(xb, w1t, c1);
    k_h2m<<<NN / 64, 256, 0, stream>>>(c1, w2t_hi, w2t_lo, h);
    k_attn<<<NB, 256, 0, stream>>>(h, attn, segoff, gram);
    k_bdh<<<dim3(NSLOT, NB), 128, 0, stream>>>(xb, attn, segoff, bdh_part, xsum_part);
    k_bdh_red<<<256, 256, 0, stream>>>(bdh_part, xsum_part, segoff, bdh, out_segment);
    k_post<<<dim3(ND / 128, KSPL), 256, 0, stream>>>(bdh, wpost, out_part);
    k_post_red<<<(NB * ND) / (256 * 4), 256, 0, stream>>>(out_part, out);
}

// Round 6
// 283.771 us; speedup vs baseline: 4.3866x; 1.1301x over previous
//
#include <hip/hip_runtime.h>
#include <hip/hip_bf16.h>

// Problem dims (fixed by setup_inputs): B=64, N=16384, D=1024, A=2048, H=8
#define NB 64
#define NN 16384
#define ND 1024
#define NA 2048
#define NH 8
#define NSLOT 16    // k_bdh frame-offset slots
#define KSPL 64     // k_post split-K chunks
#define NPL 16      // h_part planes (= NA/128 n-blocks of k_c1h)

typedef __attribute__((ext_vector_type(4))) float f32x4;
typedef __attribute__((ext_vector_type(8))) short short8;
typedef __attribute__((ext_vector_type(8))) unsigned short ushort8;

__device__ __forceinline__ unsigned short f2bf(float f) {
    unsigned int u = __float_as_uint(f);
    u = (u + 0x7fff + ((u >> 16) & 1)) >> 16;   // round-to-nearest-even
    return (unsigned short)u;
}

__device__ __forceinline__ float bf2f(unsigned short s) {
    return __uint_as_float((unsigned int)s << 16);
}

__device__ __forceinline__ void load_lds16(const void* g, void* l) {
    __builtin_amdgcn_global_load_lds((const __attribute__((address_space(1))) void*)g,
                                     (__attribute__((address_space(3))) void*)l, 16, 0, 0);
}

// ---- k_pre: segoff + cast x->xb + cast/transpose w1->w1t
__global__ __launch_bounds__(256) void k_pre(const float* __restrict__ x,
                                             const float* __restrict__ w1,
                                             const int* __restrict__ segnum,
                                             unsigned short* __restrict__ xb,
                                             unsigned short* __restrict__ w1t,
                                             int* __restrict__ segoff) {
    __shared__ unsigned short t[32][33];
    const int bx = blockIdx.x;
    if (bx < 8192) {
        size_t i = ((size_t)bx * 256 + threadIdx.x) * 8;
        float4 a = *(const float4*)(x + i);
        float4 b = *(const float4*)(x + i + 4);
        ushort8 o;
        o[0] = f2bf(a.x); o[1] = f2bf(a.y); o[2] = f2bf(a.z); o[3] = f2bf(a.w);
        o[4] = f2bf(b.x); o[5] = f2bf(b.y); o[6] = f2bf(b.z); o[7] = f2bf(b.w);
        *(ushort8*)(xb + i) = o;
    } else if (bx < 10240) {
        const int idx = bx - 8192;                 // 0..2047
        const int a0 = (idx & 63) * 32, d0 = (idx >> 6) * 32;
        const int tx = threadIdx.x & 31, ty4 = (threadIdx.x >> 5) * 4;
#pragma unroll
        for (int i = 0; i < 4; i++)
            t[tx][ty4 + i] = f2bf(w1[(size_t)(d0 + ty4 + i) * NA + a0 + tx]);
        __syncthreads();
#pragma unroll
        for (int i = 0; i < 4; i++)
            w1t[(size_t)(a0 + ty4 + i) * ND + d0 + tx] = t[ty4 + i][tx];
    } else {
        if (threadIdx.x == 0) {
            int a = 0;
            segoff[0] = 0;
            for (int b = 0; b < NB; b++) { a += segnum[b]; segoff[b + 1] = a; }
        }
    }
}

// --- k_c1h: c1 = relu(xb @ w1t^T) tile kept in LDS; h_part[by] += tile @ w2slice
// grid (N/128, A/128), block 256 (4 waves, 2x2 wave grid, 64x64 per wave)
// LDS: main loop As/Bs (32KB) unioned with epilogue c1s[128][136]; w2T hi/lo after.
__global__ __launch_bounds__(256) void k_c1h(const unsigned short* __restrict__ xb,
                                             const unsigned short* __restrict__ w1t,
                                             const float* __restrict__ w2,
                                             float* __restrict__ h_part) {
    __shared__ unsigned short SM[21760];           // 43.5KB
    unsigned short* As  = SM;                      // [128*64] (main loop)
    unsigned short* Bs  = SM + 8192;               // [128*64]
    unsigned short* c1s = SM;                      // [128][136] (epilogue, overlaps As/Bs)
    unsigned short* w2hi = SM + 17408;             // [16][136]
    unsigned short* w2lo = SM + 19584;             // [16][136]

    const int tid = threadIdx.x;
    const int wave = tid >> 6, lane = tid & 63;
    const int wm = wave & 1, wn = wave >> 1;
    const int m0 = blockIdx.x * 128, n0 = blockIdx.y * 128;
    const int quad = lane >> 4, lc = lane & 15;

    // stage w2 slice -> transposed bf16 hi/lo planes [q(16, rows 8..15 = 0)][k(128)]
    for (int i = tid; i < 2176; i += 256) { w2hi[i] = 0; w2lo[i] = 0; }
    for (int i = tid; i < 1024; i += 256) {
        int k = i >> 3, q = i & 7;
        float w = w2[(size_t)(n0 + k) * NH + q];
        unsigned short hi = f2bf(w);
        w2hi[q * 136 + k] = hi;
        w2lo[q * 136 + k] = f2bf(w - bf2f(hi));
    }

    f32x4 acc[4][4];
#pragma unroll
    for (int i = 0; i < 4; i++)
#pragma unroll
        for (int j = 0; j < 4; j++) acc[i][j] = (f32x4){0.f, 0.f, 0.f, 0.f};

    const int srow = lane >> 3;           // 0..7 within issue
    const int sg = lane & 7;              // logical granule 0..7 (8 bf16 each)

    for (int k0 = 0; k0 < ND; k0 += 64) {
        __syncthreads();
#pragma unroll
        for (int i = 0; i < 4; i++) {
            int r = wave * 32 + i * 8 + srow;
            int gc = (sg ^ (r & 7)) * 8;  // swizzled global column (bf16 units)
            load_lds16(xb + (size_t)(m0 + r) * ND + k0 + gc, As + r * 64 + sg * 8);
            load_lds16(w1t + (size_t)(n0 + r) * ND + k0 + gc, Bs + r * 64 + sg * 8);
        }
        __syncthreads();
#pragma unroll
        for (int ksub = 0; ksub < 2; ksub++) {
            short8 af[4], bf[4];
            const int lg = ksub * 4 + quad;
#pragma unroll
            for (int t = 0; t < 4; t++) {
                int m = wm * 64 + t * 16 + lc;
                af[t] = *(const short8*)&As[m * 64 + (lg ^ (m & 7)) * 8];
                int n = wn * 64 + t * 16 + lc;
                bf[t] = *(const short8*)&Bs[n * 64 + (lg ^ (n & 7)) * 8];
            }
#pragma unroll
            for (int mi = 0; mi < 4; mi++)
#pragma unroll
                for (int ni = 0; ni < 4; ni++)
                    acc[mi][ni] = __builtin_amdgcn_mfma_f32_16x16x32_bf16(
                        af[mi], bf[ni], acc[mi][ni], 0, 0, 0);
        }
    }

    // ---- epilogue: relu tile -> LDS (bf16), then tile @ w2slice via MFMA
    __syncthreads();   // all As/Bs readers done before c1s overwrite
#pragma unroll
    for (int mi = 0; mi < 4; mi++)
#pragma unroll
        for (int ni = 0; ni < 4; ni++) {
            const int col = wn * 64 + ni * 16 + lc;
#pragma unroll
            for (int r = 0; r < 4; r++) {
                const int row = wm * 64 + mi * 16 + quad * 4 + r;
                c1s[row * 136 + col] = f2bf(fmaxf(acc[mi][ni][r], 0.f));
            }
        }
    __syncthreads();

    // wave handles rows wave*32 .. +31 (2 M-tiles), K = 128 (4 steps), hi+lo B
    f32x4 hacc[2];
    hacc[0] = (f32x4){0.f, 0.f, 0.f, 0.f};
    hacc[1] = (f32x4){0.f, 0.f, 0.f, 0.f};
#pragma unroll
    for (int ks = 0; ks < 4; ks++) {
        short8 bh = *(const short8*)&w2hi[lc * 136 + ks * 32 + quad * 8];
        short8 bl = *(const short8*)&w2lo[lc * 136 + ks * 32 + quad * 8];
#pragma unroll
        for (int mt = 0; mt < 2; mt++) {
            short8 af = *(const short8*)&c1s[(wave * 32 + mt * 16 + lc) * 136 + ks * 32 + quad * 8];
            hacc[mt] = __builtin_amdgcn_mfma_f32_16x16x32_bf16(af, bh, hacc[mt], 0, 0, 0);
            hacc[mt] = __builtin_amdgcn_mfma_f32_16x16x32_bf16(af, bl, hacc[mt], 0, 0, 0);
        }
    }

    if (lc < NH) {
        float* hp = h_part + (size_t)blockIdx.y * (NN * NH);
#pragma unroll
        for (int mt = 0; mt < 2; mt++)
#pragma unroll
            for (int r = 0; r < 4; r++)
                hp[(size_t)(m0 + wave * 32 + mt * 16 + quad * 4 + r) * NH + lc] = hacc[mt][r];
    }
}

// --------- per-segment softmax -> attn (+gram fused); h = sum of NPL planes
__global__ __launch_bounds__(256) void k_attn(const float* __restrict__ h_part,
                                              float* __restrict__ attn,
                                              const int* __restrict__ segoff,
                                              float* __restrict__ gram) {
    const int b = blockIdx.x;
    const int s0 = segoff[b], s1 = segoff[b + 1];
    const int len = s1 - s0;
    const int tid = threadIdx.x;
    const int wv = tid >> 6;
    __shared__ float hl[1024 * NH];      // 32KB cache of summed h (len <= 1024 path)
    __shared__ float red[4][NH];
    __shared__ float mb[NH];
    __shared__ float sinv[NH];
    __shared__ float gred[4][64];

    float mx[NH];
#pragma unroll
    for (int q = 0; q < NH; q++) mx[q] = -1e30f;

    const bool cached = (len <= 1024);

    // pass 1: sum planes (-> LDS if cached) + max
    for (int n = s0 + tid; n < s1; n += 256) {
        float v[NH];
#pragma unroll
        for (int q = 0; q < NH; q++) v[q] = 0.f;
#pragma unroll
        for (int p = 0; p < NPL; p++) {
            const float4* hp = (const float4*)(h_part + (size_t)p * (NN * NH) + (size_t)n * NH);
            float4 u0 = hp[0], u1 = hp[1];
            v[0] += u0.x; v[1] += u0.y; v[2] += u0.z; v[3] += u0.w;
            v[4] += u1.x; v[5] += u1.y; v[6] += u1.z; v[7] += u1.w;
        }
        if (cached) {
#pragma unroll
            for (int q = 0; q < NH; q++) hl[(n - s0) * NH + q] = v[q];
        }
#pragma unroll
        for (int q = 0; q < NH; q++) mx[q] = fmaxf(mx[q], v[q]);
    }
#pragma unroll
    for (int q = 0; q < NH; q++)
        for (int o = 1; o < 64; o <<= 1) mx[q] = fmaxf(mx[q], __shfl_xor(mx[q], o));
    if ((tid & 63) == 0)
        for (int q = 0; q < NH; q++) red[wv][q] = mx[q];
    __syncthreads();
    if (tid < NH)
        mb[tid] = fmaxf(fmaxf(red[0][tid], red[1][tid]), fmaxf(red[2][tid], red[3][tid]));
    __syncthreads();

    // pass 2: sum of exp
    float sm[NH];
#pragma unroll
    for (int q = 0; q < NH; q++) sm[q] = 0.f;
    for (int n = s0 + tid; n < s1; n += 256) {
        float v[NH];
        if (cached) {
#pragma unroll
            for (int q = 0; q < NH; q++) v[q] = hl[(n - s0) * NH + q];
        } else {
#pragma unroll
            for (int q = 0; q < NH; q++) v[q] = 0.f;
#pragma unroll
            for (int p = 0; p < NPL; p++) {
                const float4* hp = (const float4*)(h_part + (size_t)p * (NN * NH) + (size_t)n * NH);
                float4 u0 = hp[0], u1 = hp[1];
                v[0] += u0.x; v[1] += u0.y; v[2] += u0.z; v[3] += u0.w;
                v[4] += u1.x; v[5] += u1.y; v[6] += u1.z; v[7] += u1.w;
            }
        }
#pragma unroll
        for (int q = 0; q < NH; q++) sm[q] += expf(v[q] - mb[q]);
    }
#pragma unroll
    for (int q = 0; q < NH; q++)
        for (int o = 1; o < 64; o <<= 1) sm[q] += __shfl_xor(sm[q], o);
    if ((tid & 63) == 0)
        for (int q = 0; q < NH; q++) red[wv][q] = sm[q];
    __syncthreads();
    if (tid < NH)
        sinv[tid] = 1.0f / (red[0][tid] + red[1][tid] + red[2][tid] + red[3][tid]);
    __syncthreads();

    // pass 3: write attn + accumulate gram
    float g[NH][NH];
#pragma unroll
    for (int i = 0; i < NH; i++)
#pragma unroll
        for (int j = 0; j < NH; j++) g[i][j] = 0.f;

    for (int n = s0 + tid; n < s1; n += 256) {
        float v[NH];
        if (cached) {
#pragma unroll
            for (int q = 0; q < NH; q++) v[q] = hl[(n - s0) * NH + q];
        } else {
#pragma unroll
            for (int q = 0; q < NH; q++) v[q] = 0.f;
#pragma unroll
            for (int p = 0; p < NPL; p++) {
                const float4* hp = (const float4*)(h_part + (size_t)p * (NN * NH) + (size_t)n * NH);
                float4 u0 = hp[0], u1 = hp[1];
                v[0] += u0.x; v[1] += u0.y; v[2] += u0.z; v[3] += u0.w;
                v[4] += u1.x; v[5] += u1.y; v[6] += u1.z; v[7] += u1.w;
            }
        }
        float a[NH];
        float* ar = &attn[(size_t)n * NH];
#pragma unroll
        for (int q = 0; q < NH; q++) { a[q] = expf(v[q] - mb[q]) * sinv[q]; ar[q] = a[q]; }
#pragma unroll
        for (int i = 0; i < NH; i++)
#pragma unroll
            for (int j = 0; j < NH; j++) g[i][j] += a[i] * a[j];
    }
#pragma unroll
    for (int i = 0; i < NH; i++)
#pragma unroll
        for (int j = 0; j < NH; j++)
            for (int o = 1; o < 64; o <<= 1) g[i][j] += __shfl_xor(g[i][j], o);

    if ((tid & 63) == 0) {
#pragma unroll
        for (int i = 0; i < NH; i++)
#pragma unroll
            for (int j = 0; j < NH; j++) gred[wv][i * NH + j] = g[i][j];
    }
    __syncthreads();
    if (tid < 64)
        gram[(size_t)b * 64 + tid] = gred[0][tid] + gred[1][tid] + gred[2][tid] + gred[3][tid];
}

// ---- bdh_part[slot][b][d][h] partial of sum_n x[n,d]*attn[n,h]; + xsum partial
// grid (NSLOT slots, 64 segs), block 128: thread owns 8 d-cols (ushort8/frame)
__global__ __launch_bounds__(128) void k_bdh(const unsigned short* __restrict__ xb,
                                             const float* __restrict__ attn,
                                             const int* __restrict__ segoff,
                                             float* __restrict__ bdh_part,
                                             float* __restrict__ xsum_part) {
    const int slot = blockIdx.x;          // 0..NSLOT-1
    const int b = blockIdx.y;
    const int s0 = segoff[b], s1 = segoff[b + 1];
    const int dl = threadIdx.x;           // 0..127 -> d = dl*8..dl*8+7

    float acc[8][NH];
    float xs[8];
#pragma unroll
    for (int dd = 0; dd < 8; dd++) {
        xs[dd] = 0.f;
#pragma unroll
        for (int q = 0; q < NH; q++) acc[dd][q] = 0.f;
    }

    for (int n = s0 + slot; n < s1; n += NSLOT) {
        ushort8 xv = *(const ushort8*)(xb + (size_t)n * ND + dl * 8);
        const float4* ap = (const float4*)&attn[(size_t)n * NH];
        float4 a0 = ap[0], a1 = ap[1];
        float aq[NH] = {a0.x, a0.y, a0.z, a0.w, a1.x, a1.y, a1.z, a1.w};
#pragma unroll
        for (int dd = 0; dd < 8; dd++) {
            float xf = bf2f(xv[dd]);
            xs[dd] += xf;
#pragma unroll
            for (int q = 0; q < NH; q++) acc[dd][q] += xf * aq[q];
        }
    }

    float* bp = bdh_part + ((size_t)slot * NB + b) * (ND * NH) + (size_t)dl * 64;
#pragma unroll
    for (int dd = 0; dd < 8; dd++) {
        *(float4*)(bp + dd * 8)     = make_float4(acc[dd][0], acc[dd][1], acc[dd][2], acc[dd][3]);
        *(float4*)(bp + dd * 8 + 4) = make_float4(acc[dd][4], acc[dd][5], acc[dd][6], acc[dd][7]);
    }
    float* xp = xsum_part + ((size_t)slot * NB + b) * ND + (size_t)dl * 8;
    *(float4*)(xp)     = make_float4(xs[0], xs[1], xs[2], xs[3]);
    *(float4*)(xp + 4) = make_float4(xs[4], xs[5], xs[6], xs[7]);
}

// ------------- reduce NSLOT slots -> bdh fp32 [64][8192]; out_segment = mean(x)
__global__ __launch_bounds__(256) void k_bdh_red(const float* __restrict__ bdh_part,
                                                 const float* __restrict__ xsum_part,
                                                 const int* __restrict__ segoff,
                                                 float* __restrict__ bdh,
                                                 float* __restrict__ out_segment) {
    const int gid = blockIdx.x * 256 + threadIdx.x;   // 0..65535
    const int b = gid >> 10, d = gid & 1023;
    float4 sa = make_float4(0.f, 0.f, 0.f, 0.f);
    float4 sb = make_float4(0.f, 0.f, 0.f, 0.f);
    float xsum = 0.f;
#pragma unroll
    for (int s = 0; s < NSLOT; s++) {
        const float* p = bdh_part + ((size_t)s * NB + b) * (ND * NH) + (size_t)d * NH;
        float4 u = ((const float4*)p)[0], v = ((const float4*)p)[1];
        sa.x += u.x; sa.y += u.y; sa.z += u.z; sa.w += u.w;
        sb.x += v.x; sb.y += v.y; sb.z += v.z; sb.w += v.w;
        xsum += xsum_part[((size_t)s * NB + b) * ND + d];
    }
    float* bp = bdh + (size_t)b * (ND * NH) + (size_t)d * NH;
    ((float4*)bp)[0] = sa;
    ((float4*)bp)[1] = sb;
    const int len = segoff[b + 1] - segoff[b];
    out_segment[(size_t)b * ND + d] = xsum / (float)len;
}

// --------------- out_part[p] = bdh[64,8192] @ w_post chunk p  (split-K KSPL)
__global__ __launch_bounds__(256) void k_post(const float* __restrict__ bdh,
                                              const float* __restrict__ wp,
                                              float* __restrict__ out_part) {
    __shared__ float as[32][68];
    __shared__ float bs[32][128];
    const int tid = threadIdx.x;
    const int n0 = blockIdx.x * 128;
    const int k0 = blockIdx.y * (8192 / KSPL);
    const int tr = tid >> 4, tc = tid & 15;

    float acc[4][8];
#pragma unroll
    for (int i = 0; i < 4; i++)
#pragma unroll
        for (int j = 0; j < 8; j++) acc[i][j] = 0.f;

    for (int kc = 0; kc < 8192 / KSPL; kc += 32) {
        __syncthreads();
        {
            int r = tid >> 2;
            int c = (tid & 3) * 8;
            const float4* gp = (const float4*)(bdh + (size_t)r * (ND * NH) + k0 + kc + c);
            float4 v0 = gp[0], v1 = gp[1];
            as[c + 0][r] = v0.x; as[c + 1][r] = v0.y; as[c + 2][r] = v0.z; as[c + 3][r] = v0.w;
            as[c + 4][r] = v1.x; as[c + 5][r] = v1.y; as[c + 6][r] = v1.z; as[c + 7][r] = v1.w;
        }
        {
            int r = tid >> 3;
            int c = (tid & 7) * 16;
            const float4* gp = (const float4*)(wp + (size_t)(k0 + kc + r) * ND + n0 + c);
            float4* sp = (float4*)&bs[r][c];
            sp[0] = gp[0]; sp[1] = gp[1]; sp[2] = gp[2]; sp[3] = gp[3];
        }
        __syncthreads();
#pragma unroll
        for (int k = 0; k < 32; k++) {
            float4 a  = *(const float4*)&as[k][tr * 4];
            float4 b0 = *(const float4*)&bs[k][tc * 8];
            float4 b1 = *(const float4*)&bs[k][tc * 8 + 4];
            float av[4] = {a.x, a.y, a.z, a.w};
            float bv[8] = {b0.x, b0.y, b0.z, b0.w, b1.x, b1.y, b1.z, b1.w};
#pragma unroll
            for (int i = 0; i < 4; i++)
#pragma unroll
                for (int j = 0; j < 8; j++) acc[i][j] += av[i] * bv[j];
        }
    }

    float* op = out_part + (size_t)blockIdx.y * (NB * ND);
#pragma unroll
    for (int i = 0; i < 4; i++)
#pragma unroll
        for (int j = 0; j < 8; j++)
            op[(size_t)(tr * 4 + i) * ND + n0 + tc * 8 + j] = acc[i][j];
}

// ------------------------------------- out = sum over KSPL k-chunk partials
__global__ __launch_bounds__(256) void k_post_red(const float* __restrict__ out_part,
                                                  float* __restrict__ out) {
    const int i = (blockIdx.x * 256 + threadIdx.x) * 4;
    float4 s = *(const float4*)(out_part + i);
#pragma unroll
    for (int p = 1; p < KSPL; p++) {
        float4 v = *(const float4*)(out_part + (size_t)p * (NB * ND) + i);
        s.x += v.x; s.y += v.y; s.z += v.z; s.w += v.w;
    }
    *(float4*)(out + i) = s;
}

extern "C" void kernel_launch(void* const* d_in, const int* in_sizes, int n_in,
                              void* d_out, int out_size, void* d_ws, size_t ws_size,
                              hipStream_t stream) {
    (void)in_sizes; (void)n_in; (void)out_size; (void)ws_size;
    const float* x      = (const float*)d_in[0];
    const int*   segnum = (const int*)d_in[1];
    const float* w1     = (const float*)d_in[2];
    const float* w2     = (const float*)d_in[3];
    const float* wpost  = (const float*)d_in[4];

    float* out         = (float*)d_out;            // [64*1024]
    float* out_segment = out + NB * ND;            // [64*1024]
    float* gram        = out + 2 * NB * ND;        // [64*64]

    char* ws = (char*)d_ws;
    const size_t MB = 1024 * 1024;
    // layout (peak 100 MB):
    int*   segoff   = (int*)ws;                                    // 1KB   @0
    float* attn     = (float*)(ws + 1 * MB);                       // 512KB @1MB
    float* bdh      = (float*)(ws + 2 * MB);                       // 2MB   @2MB
    float* h_part   = (float*)(ws + 4 * MB);                       // 8MB   @4MB
    unsigned short* xb  = (unsigned short*)(ws + 12 * MB);         // 32MB  @12MB
    unsigned short* w1t = (unsigned short*)(ws + 44 * MB);         // 4MB   @44MB
    float* bdh_part  = (float*)(ws + 48 * MB);                     // 32MB  @48MB
    float* xsum_part = (float*)(ws + 80 * MB);                     // 4MB   @80MB
    float* out_part  = (float*)(ws + 84 * MB);                     // 16MB  @84MB

    k_pre<<<10241, 256, 0, stream>>>(x, w1, segnum, xb, w1t, segoff);
    k_c1h<<<dim3(NN / 128, NA / 128), 256, 0, stream>>>(xb, w1t, w2, h_part);
    k_attn<<<NB, 256, 0, stream>>>(h_part, attn, segoff, gram);
    k_bdh<<<dim3(NSLOT, NB), 128, 0, stream>>>(xb, attn, segoff, bdh_part, xsum_part);
    k_bdh_red<<<256, 256, 0, stream>>>(bdh_part, xsum_part, segoff, bdh, out_segment);
    k_post<<<dim3(ND / 128, KSPL), 256, 0, stream>>>(bdh, wpost, out_part);
    k_post_red<<<(NB * ND) / (256 * 4), 256, 0, stream>>>(out_part, out);
}